// Round 6
// baseline (165.884 us; speedup 1.0000x reference)
//
#include <hip/hip_runtime.h>

#define Bn 8
#define Nn 10647
#define Cn 80
#define MAXB 100
#define SCORE_TH 0.3f
#define BGUESS 0.79f      // cache admission threshold (mean 253/class, sigma ~16)
#define IOU_THR 0.5f
#define NBIN 4096
#define SORT_CAP 256      // slow-path chunk size
#define TARGET 160
#define GCAP 400          // per-(b,c) cached candidate capacity (+9.4 sigma)
#define LCAP 512
#define TOT (Cn * MAXB)   // 8000
#define TOTQ (TOT / 4)    // 2000
#define MREG 8
#define ABLK 256          // chunks per batch in collect -> 2048 blocks

// bin index monotone non-decreasing in score; scores in (0.3, 1) -> bins [1, 3688]
__device__ __forceinline__ int score_bin(float s) {
    int v = (int)(__float_as_uint(s) >> 12) - 0x3E999 + 1;
    v = v < 1 ? 1 : v;
    return v > NBIN - 1 ? NBIN - 1 : v;
}

// IoU exactly as reference (symmetric in its two args)
__device__ __forceinline__ bool iou_gt(const float4 s, const float4 c) {
    float x1 = fmaxf(s.x, c.x);
    float y1 = fmaxf(s.y, c.y);
    float x2 = fminf(s.z, c.z);
    float y2 = fminf(s.w, c.w);
    float inter = fmaxf(x2 - x1, 0.0f) * fmaxf(y2 - y1, 0.0f);
    float aS = (s.z - s.x) * (s.w - s.y);
    float aC = (c.z - c.x) * (c.w - c.y);
    return inter / (aS + aC - inter + 1e-9f) > IOU_THR;
}

// Kernel A: one coalesced pass over cp. Appends s>BGUESS candidates to
// per-(b,c) global lists; counts all s>SCORE_TH per class (LDS-aggregated).
__global__ __launch_bounds__(256) void collect(
    const float* __restrict__ conf, const float* __restrict__ cp,
    int* __restrict__ gcnt, int* __restrict__ tcnt,
    unsigned long long* __restrict__ glist)
{
    __shared__ int lcnt[Cn];
    int tid = threadIdx.x;
    int b = blockIdx.x / ABLK;
    int chunk = blockIdx.x % ABLK;
    for (int i = tid; i < Cn; i += 256) lcnt[i] = 0;
    __syncthreads();

    const float4* cp4 = (const float4*)(cp + (size_t)b * Nn * Cn);
    const float* confB = conf + b * Nn;
    const int totq = Nn * 20;                       // 212940 float4 per batch
    const int per = (totq + ABLK - 1) / ABLK;       // 832
    int q0 = chunk * per;
    int q1 = q0 + per; if (q1 > totq) q1 = totq;

    for (int q = q0 + tid; q < q1; q += 256) {      // ~3.25 iters
        float4 v = cp4[q];
        int n = q / 20;
        int c0 = (q % 20) * 4;
        float cf = confB[n];                        // L1 broadcast (20 threads share)
        float sv[4] = {v.x, v.y, v.z, v.w};
#pragma unroll
        for (int e = 0; e < 4; ++e) {
            float s = cf * sv[e];
            if (s > SCORE_TH) {
                atomicAdd(&lcnt[c0 + e], 1);
                if (s > BGUESS) {
                    int bc = b * Cn + c0 + e;
                    int pos = atomicAdd(&gcnt[bc], 1);
                    if (pos < GCAP)
                        glist[(size_t)bc * GCAP + pos] =
                            ((unsigned long long)__float_as_uint(s) << 32) |
                            (unsigned)(Nn - 1 - n);
                }
            }
        }
    }
    __syncthreads();
    for (int i = tid; i < Cn; i += 256)
        if (lcnt[i]) atomicAdd(&tcnt[b * Cn + i], lcnt[i]);
}

// Kernel B: per-(b,c) NMS from the cached list. Rank-sort + broadcast triangle
// + run-append walk. Exact slow-path fallback (histogram multi-round, strided
// reads) if cache insufficient — probability ~0, correctness guaranteed.
__global__ __launch_bounds__(256) void nms_class(
    const float* __restrict__ boxes, const float* __restrict__ conf,
    const float* __restrict__ cp,
    const int* __restrict__ gcnt, const int* __restrict__ tcnt,
    const unsigned long long* __restrict__ glist,
    float* __restrict__ wss, float4* __restrict__ wsb)
{
    __shared__ unsigned long long keys[LCAP];    // 4 KB
    __shared__ unsigned long long skeys[LCAP];   // 4 KB
    __shared__ float4 sbx[LCAP];                 // 8 KB
    __shared__ unsigned char confl[LCAP];
    __shared__ int hist[NBIN];                   // 16 KB (slow path only)
    __shared__ int suf[257];
    __shared__ int wtot[4];
    __shared__ int sh_B, sh_M, sh_nsel;

    int tid = threadIdx.x;
    int lane = tid & 63, wv = tid >> 6;
    int bc = blockIdx.x;
    int b = bc / Cn, c = bc % Cn;

    int cnt = gcnt[bc];
    int tot = tcnt[bc];
    bool fast = (cnt <= GCAP);
    int M = fast ? cnt : 0;

    float* ws_s = wss + bc * MAXB;
    float4* ws_b = wsb + bc * MAXB;
    for (int i = tid; i < MAXB; i += 256) ws_s[i] = 0.0f;
    if (tid == 0) sh_nsel = 0;

    for (int i = tid; i < LCAP; i += 256)
        keys[i] = (i < M) ? glist[(size_t)bc * GCAP + i] : 0ULL;
    __syncthreads();

    const float4* boxesB = (const float4*)boxes + (size_t)b * Nn;

    // ---------- fast path ----------
    {
        unsigned long long k0 = keys[tid], k1 = keys[tid + 256];
        float4 b0 = make_float4(0, 0, 0, 0), b1 = make_float4(0, 0, 0, 0);
        if (tid < M) b0 = boxesB[Nn - 1 - (int)(k0 & 0xffffffffu)];
        if (tid + 256 < M) b1 = boxesB[Nn - 1 - (int)(k1 & 0xffffffffu)];
        // rank-sort (keys unique; uniform j-loop -> LDS broadcast, no barriers)
        int r0 = 0, r1 = 0;
        for (int j = 0; j < M; ++j) {
            unsigned long long kk = keys[j];
            if (kk > k0) ++r0;
            if (kk > k1) ++r1;
        }
        if (tid < M) { skeys[r0] = k0; sbx[r0] = b0; }
        if (tid + 256 < M) { skeys[r1] = k1; sbx[r1] = b1; }
        __syncthreads();

        // triangle conflict pass (broadcast reads)
        bool cf0 = false, cf1 = false;
        float4 t0 = sbx[tid], t1 = sbx[tid + 256];
        int bound = (tid + 256 < M) ? (tid + 256) : ((tid < M) ? tid : 0);
        for (int i = 0; i < bound; ++i) {
            float4 bi = sbx[i];
            if (i < tid && iou_gt(bi, t0)) cf0 = true;
            if (iou_gt(bi, t1)) cf1 = true;
        }
        confl[tid] = cf0 ? 1 : 0;
        confl[tid + 256] = cf1 ? 1 : 0;
        __syncthreads();

        // walk: wave 0; conflict-free -> parallel run-append, else exact ballot
        if (tid < 64) {
            float4 sA = make_float4(0, 0, 0, 0), sB = make_float4(0, 0, 0, 0);
            int nsel = 0;
            for (int w0 = 0; w0 < M && nsel < MAXB; w0 += 64) {
                int wlim = M - w0; if (wlim > 64) wlim = 64;
                bool cfl = (tid < wlim) ? (confl[w0 + tid] != 0) : false;
                unsigned long long cmask = __ballot(cfl);
                int pos = 0;
                while (pos < wlim && nsel < MAXB) {
                    if (!((cmask >> pos) & 1ULL)) {
                        unsigned long long rest = cmask >> pos;
                        int run = rest ? (__ffsll(rest) - 1) : (wlim - pos);
                        if (run > wlim - pos) run = wlim - pos;
                        int avail = MAXB - nsel; if (run > avail) run = avail;
                        int d = (tid - (nsel & 63)) & 63;
                        if (d < run) {
                            int s = nsel + d;
                            int ci = w0 + pos + d;
                            float4 bx = sbx[ci];
                            if (s < 64) sA = bx; else sB = bx;
                            ws_s[s] = __uint_as_float((unsigned)(skeys[ci] >> 32));
                            ws_b[s] = bx;
                        }
                        nsel += run; pos += run;
                    } else {
                        int ci = w0 + pos;
                        float4 bx = sbx[ci];
                        bool sup = (tid < nsel) && iou_gt(sA, bx);
                        if (tid + 64 < nsel) sup = sup || iou_gt(sB, bx);
                        if (__ballot(sup) == 0ULL) {
                            if (tid == (nsel & 63)) { if (nsel < 64) sA = bx; else sB = bx; }
                            if (tid == 0) {
                                ws_s[nsel] = __uint_as_float((unsigned)(skeys[ci] >> 32));
                                ws_b[nsel] = bx;
                            }
                            ++nsel;
                        }
                        ++pos;
                    }
                }
            }
            if (tid == 0) sh_nsel = nsel;
        }
        __syncthreads();
    }

    // done iff walk filled MAXB, or every existing candidate was cached+processed
    bool needSlow = (!fast) || !((sh_nsel >= MAXB) || (cnt == tot));
    if (!needSlow) return;

    // ---------- slow path: exact full redo (never taken in practice) ----------
    for (int i = tid; i < MAXB; i += 256) ws_s[i] = 0.0f;
    for (int i = tid; i < NBIN / 4; i += 256) ((int4*)hist)[i] = make_int4(0, 0, 0, 0);
    if (tid == 0) sh_nsel = 0;
    __syncthreads();

    const float* confB = conf + b * Nn;
    const float* cpB = cp + (size_t)b * Nn * Cn + c;
    for (int n = tid; n < Nn; n += 256) {
        float s = confB[n] * cpB[(size_t)n * Cn];
        if (s > SCORE_TH) atomicAdd(&hist[score_bin(s)], 1);
    }
    __syncthreads();

    float4 sA = make_float4(0, 0, 0, 0), sB = make_float4(0, 0, 0, 0);
    int hi = NBIN;
    int round = 0;

    while (true) {
        int ps = 0;
#pragma unroll
        for (int u = 0; u < 16; ++u) ps += hist[tid * 16 + u];
        int p = ps;
#pragma unroll
        for (int off = 1; off < 64; off <<= 1) {
            int v = __shfl_down(p, off);
            if (lane + off < 64) p += v;
        }
        if (lane == 0) wtot[wv] = p;
        __syncthreads();
        int add = 0;
        for (int w2 = wv + 1; w2 < 4; ++w2) add += wtot[w2];
        suf[tid] = p + add;
        if (tid == 0) suf[256] = 0;
        __syncthreads();

        int total = suf[0];
        if (total == 0) break;

        int target = total < TARGET ? total : TARGET;
        if (suf[tid] >= target && suf[tid + 1] < target) sh_B = tid;
        if (tid == 0) sh_M = 0;
        __syncthreads();
        if (tid == 0) {
            int g = sh_B;
            int running = suf[g + 1];
            int B = g * 16;
            for (int u = 15; u >= 0; --u) {
                running += hist[g * 16 + u];
                if (running >= target) { B = g * 16 + u; break; }
            }
            sh_B = B;
        }
        __syncthreads();
        int B = sh_B;

        for (int n = tid; n < Nn; n += 256) {
            float s = confB[n] * cpB[(size_t)n * Cn];
            if (s > SCORE_TH) {
                int bin = score_bin(s);
                if (bin >= B && bin < hi) {
                    int pos2 = atomicAdd(&sh_M, 1);
                    if (pos2 < SORT_CAP)
                        keys[pos2] = ((unsigned long long)__float_as_uint(s) << 32) |
                                     (unsigned)(Nn - 1 - n);
                }
            }
        }
        __syncthreads();
        int M2 = sh_M; if (M2 > SORT_CAP) M2 = SORT_CAP;

        unsigned long long mykey = (tid < M2) ? keys[tid] : 0ULL;
        float4 mybox = make_float4(0, 0, 0, 0);
        if (tid < M2) mybox = boxesB[Nn - 1 - (int)(mykey & 0xffffffffu)];
        int rank = 0;
        for (int j = 0; j < M2; ++j) rank += (keys[j] > mykey) ? 1 : 0;
        if (tid < M2) { skeys[rank] = mykey; sbx[rank] = mybox; }
        __syncthreads();

        bool cfl = (round > 0);
        if (round == 0 && tid < M2) {
            float4 tb = sbx[tid];
            for (int i = 0; i < tid; ++i)
                if (iou_gt(sbx[i], tb)) cfl = true;
        }
        confl[tid] = cfl ? 1 : 0;
        __syncthreads();

        if (tid < 64) {
            int nsel = sh_nsel;
            for (int w0 = 0; w0 < M2 && nsel < MAXB; w0 += 64) {
                int wlim = M2 - w0; if (wlim > 64) wlim = 64;
                bool cfl2 = (tid < wlim) ? (confl[w0 + tid] != 0) : false;
                unsigned long long cmask = __ballot(cfl2);
                int pos = 0;
                while (pos < wlim && nsel < MAXB) {
                    if (!((cmask >> pos) & 1ULL)) {
                        unsigned long long rest = cmask >> pos;
                        int run = rest ? (__ffsll(rest) - 1) : (wlim - pos);
                        if (run > wlim - pos) run = wlim - pos;
                        int avail = MAXB - nsel; if (run > avail) run = avail;
                        int d = (tid - (nsel & 63)) & 63;
                        if (d < run) {
                            int s = nsel + d;
                            int ci = w0 + pos + d;
                            float4 bx = sbx[ci];
                            if (s < 64) sA = bx; else sB = bx;
                            ws_s[s] = __uint_as_float((unsigned)(skeys[ci] >> 32));
                            ws_b[s] = bx;
                        }
                        nsel += run; pos += run;
                    } else {
                        int ci = w0 + pos;
                        float4 bx = sbx[ci];
                        bool sup = (tid < nsel) && iou_gt(sA, bx);
                        if (tid + 64 < nsel) sup = sup || iou_gt(sB, bx);
                        if (__ballot(sup) == 0ULL) {
                            if (tid == (nsel & 63)) { if (nsel < 64) sA = bx; else sB = bx; }
                            if (tid == 0) {
                                ws_s[nsel] = __uint_as_float((unsigned)(skeys[ci] >> 32));
                                ws_b[nsel] = bx;
                            }
                            ++nsel;
                        }
                        ++pos;
                    }
                }
            }
            if (tid == 0) sh_nsel = nsel;
        }
        __syncthreads();
        if (sh_nsel >= MAXB) break;
        for (int i = B + tid; i < NBIN; i += 256) hist[i] = 0;
        hi = B;
        ++round;
        __syncthreads();
    }
}

// Kernel C: per-batch top-100 of 8000: register-cached input, wave-shuffle
// suffix scan, histogram select, rank-sort.
__global__ __launch_bounds__(256) void merge_topk(
    const float* __restrict__ wss, const float4* __restrict__ wsb,
    float* __restrict__ out)
{
    __shared__ int hist[NBIN];
    __shared__ int suf[257];
    __shared__ int wtot[4];
    __shared__ unsigned long long keys[SORT_CAP];
    __shared__ unsigned long long skeys[SORT_CAP];
    __shared__ int sh_B, sh_M;

    int tid = threadIdx.x, b = blockIdx.x;
    int lane = tid & 63, wv = tid >> 6;
    for (int i = tid; i < NBIN / 4; i += 256) ((int4*)hist)[i] = make_int4(0, 0, 0, 0);
    if (tid == 0) sh_M = 0;
    skeys[tid] = 0ULL;
    __syncthreads();

    const float4* w4 = (const float4*)(wss + b * TOT);
    float4 rr[MREG];
#pragma unroll
    for (int k = 0; k < MREG; ++k) {
        int q = tid + k * 256;
        rr[k] = (q < TOTQ) ? w4[q] : make_float4(0, 0, 0, 0);
    }
#pragma unroll
    for (int k = 0; k < MREG; ++k) {
        float4 v = rr[k];
        if (v.x > 0.0f) atomicAdd(&hist[score_bin(v.x)], 1);
        if (v.y > 0.0f) atomicAdd(&hist[score_bin(v.y)], 1);
        if (v.z > 0.0f) atomicAdd(&hist[score_bin(v.z)], 1);
        if (v.w > 0.0f) atomicAdd(&hist[score_bin(v.w)], 1);
    }
    __syncthreads();

    int ps = 0;
#pragma unroll
    for (int u = 0; u < 16; ++u) ps += hist[tid * 16 + u];
    int p = ps;
#pragma unroll
    for (int off = 1; off < 64; off <<= 1) {
        int v = __shfl_down(p, off);
        if (lane + off < 64) p += v;
    }
    if (lane == 0) wtot[wv] = p;
    __syncthreads();
    int add = 0;
    for (int w2 = wv + 1; w2 < 4; ++w2) add += wtot[w2];
    suf[tid] = p + add;
    if (tid == 0) suf[256] = 0;
    __syncthreads();

    int total = suf[0];
    int target = total < MAXB ? total : MAXB;

    if (total > 0) {
        if (suf[tid] >= target && suf[tid + 1] < target) sh_B = tid;
    }
    __syncthreads();
    if (total > 0 && tid == 0) {
        int g = sh_B;
        int running = suf[g + 1];
        int B = g * 16;
        for (int u = 15; u >= 0; --u) {
            running += hist[g * 16 + u];
            if (running >= target) { B = g * 16 + u; break; }
        }
        sh_B = B;
    }
    __syncthreads();
    if (total > 0) {
        int B = sh_B;
#pragma unroll
        for (int k = 0; k < MREG; ++k) {
            int q = tid + k * 256;
            if (q < TOTQ) {
                float4 v = rr[k];
                int ib = q * 4;
                float sv[4] = {v.x, v.y, v.z, v.w};
#pragma unroll
                for (int e = 0; e < 4; ++e) {
                    float s = sv[e];
                    if (s > 0.0f && score_bin(s) >= B) {
                        int pos = atomicAdd(&sh_M, 1);
                        if (pos < SORT_CAP)
                            keys[pos] = ((unsigned long long)__float_as_uint(s) << 32) |
                                        (unsigned)(TOT - 1 - (ib + e));
                    }
                }
            }
        }
    }
    __syncthreads();
    int M = sh_M; if (M > SORT_CAP) M = SORT_CAP;

    unsigned long long mykey = (tid < M) ? keys[tid] : 0ULL;
    int rank = 0;
    for (int j = 0; j < M; ++j) rank += (keys[j] > mykey) ? 1 : 0;
    if (tid < M) skeys[rank] = mykey;
    __syncthreads();

    bool valid = false;
    if (tid < MAXB) {
        unsigned long long g = skeys[tid];
        valid = (g != 0ULL);
        float s = valid ? __uint_as_float((unsigned)(g >> 32)) : 0.0f;
        int f = TOT - 1 - (int)(g & 0xffffffffu);
        float4 bx = make_float4(0, 0, 0, 0);
        float cls = 0.0f;
        if (valid) { bx = wsb[b * TOT + f]; cls = (float)(f / MAXB); }
        ((float4*)out)[b * MAXB + tid] = bx;                          // sel_b
        out[Bn * MAXB * 4 + b * MAXB + tid] = s;                      // sel_s
        out[Bn * MAXB * 5 + b * MAXB + tid] = cls;                    // sel_c
    }
    int nv = __syncthreads_count(valid);
    if (tid == 0) out[Bn * MAXB * 6 + b] = (float)nv;                 // num_valid
}

extern "C" void kernel_launch(void* const* d_in, const int* in_sizes, int n_in,
                              void* d_out, int out_size, void* d_ws, size_t ws_size,
                              hipStream_t stream) {
    const float* boxes = (const float*)d_in[0];
    const float* conf  = (const float*)d_in[1];
    const float* cp    = (const float*)d_in[2];
    float* out = (float*)d_out;

    // workspace layout (all offsets 256-aligned where it matters):
    // [0, 2560)        gcnt[640]
    // [2560, 5120)     tcnt[640]
    // [5376, +2048000) glist[640*400] u64
    // offWss           wss[640*100] f32   (16B-aligned)
    // offWsb           wsb[640*100] float4
    char* ws = (char*)d_ws;
    int* gcnt = (int*)(ws + 0);
    int* tcnt = (int*)(ws + 2560);
    unsigned long long* glist = (unsigned long long*)(ws + 5376);
    size_t offWss = 5376 + (size_t)640 * GCAP * 8;          // 2053376
    offWss = (offWss + 255) & ~(size_t)255;
    size_t offWsb = offWss + (size_t)640 * MAXB * 4;        // +256000
    offWsb = (offWsb + 255) & ~(size_t)255;
    float* wss = (float*)(ws + offWss);
    float4* wsb = (float4*)(ws + offWsb);

    hipMemsetAsync(d_ws, 0, 5376, stream);   // zero gcnt + tcnt
    collect<<<Bn * ABLK, 256, 0, stream>>>(conf, cp, gcnt, tcnt, glist);
    nms_class<<<Bn * Cn, 256, 0, stream>>>(boxes, conf, cp, gcnt, tcnt, glist,
                                           wss, wsb);
    merge_topk<<<Bn, 256, 0, stream>>>(wss, wsb, out);
}

// Round 7
// 124.140 us; speedup vs baseline: 1.3363x; 1.3363x over previous
//
#include <hip/hip_runtime.h>

#define Bn 8
#define Nn 10647
#define Cn 80
#define MAXB 100
#define SCORE_TH 0.3f
#define BGUESS 0.79f      // cache admission threshold (mean 253/class, sigma ~16)
#define IOU_THR 0.5f
#define NBIN 4096
#define SORT_CAP 256      // slow-path chunk size
#define TARGET 160
#define GCAP 400          // per-(b,c) cached candidate capacity (+9.4 sigma)
#define LCAP 512
#define TRI 192           // triangle/walk chunk (walk needs ~115; 8-sigma margin)
#define TOT (Cn * MAXB)   // 8000
#define TOTQ (TOT / 4)    // 2000
#define MREG 8
#define ABLK 256          // chunks per batch in collect -> 2048 blocks

// bin index monotone non-decreasing in score; scores in (0.3, 1) -> bins [1, 3688]
__device__ __forceinline__ int score_bin(float s) {
    int v = (int)(__float_as_uint(s) >> 12) - 0x3E999 + 1;
    v = v < 1 ? 1 : v;
    return v > NBIN - 1 ? NBIN - 1 : v;
}

// IoU exactly as reference (symmetric in its two args)
__device__ __forceinline__ bool iou_gt(const float4 s, const float4 c) {
    float x1 = fmaxf(s.x, c.x);
    float y1 = fmaxf(s.y, c.y);
    float x2 = fminf(s.z, c.z);
    float y2 = fminf(s.w, c.w);
    float inter = fmaxf(x2 - x1, 0.0f) * fmaxf(y2 - y1, 0.0f);
    float aS = (s.z - s.x) * (s.w - s.y);
    float aC = (c.z - c.x) * (c.w - c.y);
    return inter / (aS + aC - inter + 1e-9f) > IOU_THR;
}

// Kernel A: one coalesced pass over cp. Appends s>BGUESS candidates to
// per-(b,c) global lists; counts all s>SCORE_TH per class (LDS-aggregated).
__global__ __launch_bounds__(256) void collect(
    const float* __restrict__ conf, const float* __restrict__ cp,
    int* __restrict__ gcnt, int* __restrict__ tcnt,
    unsigned long long* __restrict__ glist)
{
    __shared__ int lcnt[Cn];
    int tid = threadIdx.x;
    int b = blockIdx.x / ABLK;
    int chunk = blockIdx.x % ABLK;
    for (int i = tid; i < Cn; i += 256) lcnt[i] = 0;
    __syncthreads();

    const float4* cp4 = (const float4*)(cp + (size_t)b * Nn * Cn);
    const float* confB = conf + b * Nn;
    const int totq = Nn * 20;                       // 212940 float4 per batch
    const int per = (totq + ABLK - 1) / ABLK;       // 832
    int q0 = chunk * per;
    int q1 = q0 + per; if (q1 > totq) q1 = totq;

    for (int q = q0 + tid; q < q1; q += 256) {      // ~3.25 iters
        float4 v = cp4[q];
        int n = q / 20;
        int c0 = (q % 20) * 4;
        float cf = confB[n];                        // near-uniform -> L1 broadcast
        float sv[4] = {v.x, v.y, v.z, v.w};
#pragma unroll
        for (int e = 0; e < 4; ++e) {
            float s = cf * sv[e];
            if (s > SCORE_TH) {
                atomicAdd(&lcnt[c0 + e], 1);
                if (s > BGUESS) {
                    int bc = b * Cn + c0 + e;
                    int pos = atomicAdd(&gcnt[bc], 1);
                    if (pos < GCAP)
                        glist[(size_t)bc * GCAP + pos] =
                            ((unsigned long long)__float_as_uint(s) << 32) |
                            (unsigned)(Nn - 1 - n);
                }
            }
        }
    }
    __syncthreads();
    for (int i = tid; i < Cn; i += 256)
        if (lcnt[i]) atomicAdd(&tcnt[b * Cn + i], lcnt[i]);
}

// Kernel B: per-(b,c) NMS from the cached list. 2-key rank-sort of all cnt;
// triangle + run-append walk over first TRI sorted only; exact ballot
// remainder; exact slow-path full redo (never taken) if cache insufficient.
__global__ __launch_bounds__(256) void nms_class(
    const float* __restrict__ boxes, const float* __restrict__ conf,
    const float* __restrict__ cp,
    const int* __restrict__ gcnt, const int* __restrict__ tcnt,
    const unsigned long long* __restrict__ glist,
    float* __restrict__ wss, float4* __restrict__ wsb)
{
    __shared__ unsigned long long keys[LCAP];    // 4 KB
    __shared__ unsigned long long skeys[LCAP];   // 4 KB
    __shared__ float4 sbx[LCAP];                 // 8 KB
    __shared__ unsigned char confl[LCAP];
    __shared__ int hist[NBIN];                   // 16 KB (slow path only)
    __shared__ int suf[257];
    __shared__ int wtot[4];
    __shared__ int sh_B, sh_M, sh_nsel;

    int tid = threadIdx.x;
    int lane = tid & 63, wv = tid >> 6;
    int bc = blockIdx.x;
    int b = bc / Cn, c = bc % Cn;

    int cnt = gcnt[bc];
    int tot = tcnt[bc];
    bool fast = (cnt <= GCAP);
    int M = fast ? cnt : 0;

    float* ws_s = wss + bc * MAXB;
    float4* ws_b = wsb + bc * MAXB;
    for (int i = tid; i < MAXB; i += 256) ws_s[i] = 0.0f;
    if (tid == 0) sh_nsel = 0;

    for (int i = tid; i < LCAP; i += 256)
        keys[i] = (i < M) ? glist[(size_t)bc * GCAP + i] : 0ULL;
    __syncthreads();

    const float4* boxesB = (const float4*)boxes + (size_t)b * Nn;

    // ---------- fast path ----------
    {
        unsigned long long k0 = keys[tid], k1 = keys[tid + 256];
        float4 b0 = make_float4(0, 0, 0, 0), b1 = make_float4(0, 0, 0, 0);
        if (tid < M) b0 = boxesB[Nn - 1 - (int)(k0 & 0xffffffffu)];
        if (tid + 256 < M) b1 = boxesB[Nn - 1 - (int)(k1 & 0xffffffffu)];
        // rank-sort (keys unique; uniform j-loop -> LDS broadcast, no barriers)
        int r0 = 0, r1 = 0;
        for (int j = 0; j < M; ++j) {
            unsigned long long kk = keys[j];
            if (kk > k0) ++r0;
            if (kk > k1) ++r1;
        }
        if (tid < M) { skeys[r0] = k0; sbx[r0] = b0; }
        if (tid + 256 < M) { skeys[r1] = k1; sbx[r1] = b1; }
        __syncthreads();

        // triangle conflict pass over first T sorted only; 2-way unrolled ILP
        int T = M < TRI ? M : TRI;
        bool cf0 = false;
        if (tid < T) {
            float4 tb = sbx[tid];
            bool fa = false, fb = false;
            int i = 0;
            for (; i + 1 < tid; i += 2) {
                float4 ba = sbx[i], bb2 = sbx[i + 1];   // independent loads
                fa = fa || iou_gt(ba, tb);
                fb = fb || iou_gt(bb2, tb);
            }
            if (i < tid) fa = fa || iou_gt(sbx[i], tb);
            cf0 = fa || fb;
        }
        confl[tid] = cf0 ? 1 : 0;
        __syncthreads();

        // walk: wave 0; chunk 0 = first T with run-append; remainder ballot-only
        if (tid < 64) {
            float4 sA = make_float4(0, 0, 0, 0), sB = make_float4(0, 0, 0, 0);
            int nsel = 0;
            for (int w0 = 0; w0 < T && nsel < MAXB; w0 += 64) {
                int wlim = T - w0; if (wlim > 64) wlim = 64;
                bool cfl = (tid < wlim) ? (confl[w0 + tid] != 0) : false;
                unsigned long long cmask = __ballot(cfl);
                int pos = 0;
                while (pos < wlim && nsel < MAXB) {
                    if (!((cmask >> pos) & 1ULL)) {
                        unsigned long long rest = cmask >> pos;
                        int run = rest ? (__ffsll(rest) - 1) : (wlim - pos);
                        if (run > wlim - pos) run = wlim - pos;
                        int avail = MAXB - nsel; if (run > avail) run = avail;
                        int d = (tid - (nsel & 63)) & 63;
                        if (d < run) {
                            int s = nsel + d;
                            int ci = w0 + pos + d;
                            float4 bx = sbx[ci];
                            if (s < 64) sA = bx; else sB = bx;
                            ws_s[s] = __uint_as_float((unsigned)(skeys[ci] >> 32));
                            ws_b[s] = bx;
                        }
                        nsel += run; pos += run;
                    } else {
                        int ci = w0 + pos;
                        float4 bx = sbx[ci];
                        bool sup = (tid < nsel) && iou_gt(sA, bx);
                        if (tid + 64 < nsel) sup = sup || iou_gt(sB, bx);
                        if (__ballot(sup) == 0ULL) {
                            if (tid == (nsel & 63)) { if (nsel < 64) sA = bx; else sB = bx; }
                            if (tid == 0) {
                                ws_s[nsel] = __uint_as_float((unsigned)(skeys[ci] >> 32));
                                ws_b[nsel] = bx;
                            }
                            ++nsel;
                        }
                        ++pos;
                    }
                }
            }
            // remainder [T, M): exact per-candidate ballot (essentially never)
            for (int ci = T; ci < M && nsel < MAXB; ++ci) {
                float4 bx = sbx[ci];
                bool sup = (tid < nsel) && iou_gt(sA, bx);
                if (tid + 64 < nsel) sup = sup || iou_gt(sB, bx);
                if (__ballot(sup) == 0ULL) {
                    if (tid == (nsel & 63)) { if (nsel < 64) sA = bx; else sB = bx; }
                    if (tid == 0) {
                        ws_s[nsel] = __uint_as_float((unsigned)(skeys[ci] >> 32));
                        ws_b[nsel] = bx;
                    }
                    ++nsel;
                }
            }
            if (tid == 0) sh_nsel = nsel;
        }
        __syncthreads();
    }

    // done iff walk filled MAXB, or every existing candidate was cached+processed
    bool needSlow = (!fast) || !((sh_nsel >= MAXB) || (cnt == tot));
    if (!needSlow) return;

    // ---------- slow path: exact full redo (never taken in practice) ----------
    for (int i = tid; i < MAXB; i += 256) ws_s[i] = 0.0f;
    for (int i = tid; i < NBIN / 4; i += 256) ((int4*)hist)[i] = make_int4(0, 0, 0, 0);
    if (tid == 0) sh_nsel = 0;
    __syncthreads();

    const float* confB = conf + b * Nn;
    const float* cpB = cp + (size_t)b * Nn * Cn + c;
    for (int n = tid; n < Nn; n += 256) {
        float s = confB[n] * cpB[(size_t)n * Cn];
        if (s > SCORE_TH) atomicAdd(&hist[score_bin(s)], 1);
    }
    __syncthreads();

    float4 sA = make_float4(0, 0, 0, 0), sB = make_float4(0, 0, 0, 0);
    int hi = NBIN;
    int round = 0;

    while (true) {
        int ps = 0;
#pragma unroll
        for (int u = 0; u < 16; ++u) ps += hist[tid * 16 + u];
        int p = ps;
#pragma unroll
        for (int off = 1; off < 64; off <<= 1) {
            int v = __shfl_down(p, off);
            if (lane + off < 64) p += v;
        }
        if (lane == 0) wtot[wv] = p;
        __syncthreads();
        int add = 0;
        for (int w2 = wv + 1; w2 < 4; ++w2) add += wtot[w2];
        suf[tid] = p + add;
        if (tid == 0) suf[256] = 0;
        __syncthreads();

        int total = suf[0];
        if (total == 0) break;

        int target = total < TARGET ? total : TARGET;
        if (suf[tid] >= target && suf[tid + 1] < target) sh_B = tid;
        if (tid == 0) sh_M = 0;
        __syncthreads();
        if (tid == 0) {
            int g = sh_B;
            int running = suf[g + 1];
            int B = g * 16;
            for (int u = 15; u >= 0; --u) {
                running += hist[g * 16 + u];
                if (running >= target) { B = g * 16 + u; break; }
            }
            sh_B = B;
        }
        __syncthreads();
        int B = sh_B;

        for (int n = tid; n < Nn; n += 256) {
            float s = confB[n] * cpB[(size_t)n * Cn];
            if (s > SCORE_TH) {
                int bin = score_bin(s);
                if (bin >= B && bin < hi) {
                    int pos2 = atomicAdd(&sh_M, 1);
                    if (pos2 < SORT_CAP)
                        keys[pos2] = ((unsigned long long)__float_as_uint(s) << 32) |
                                     (unsigned)(Nn - 1 - n);
                }
            }
        }
        __syncthreads();
        int M2 = sh_M; if (M2 > SORT_CAP) M2 = SORT_CAP;

        unsigned long long mykey = (tid < M2) ? keys[tid] : 0ULL;
        float4 mybox = make_float4(0, 0, 0, 0);
        if (tid < M2) mybox = boxesB[Nn - 1 - (int)(mykey & 0xffffffffu)];
        int rank = 0;
        for (int j = 0; j < M2; ++j) rank += (keys[j] > mykey) ? 1 : 0;
        if (tid < M2) { skeys[rank] = mykey; sbx[rank] = mybox; }
        __syncthreads();

        bool cfl = (round > 0);
        if (round == 0 && tid < M2) {
            float4 tb = sbx[tid];
            for (int i = 0; i < tid; ++i)
                if (iou_gt(sbx[i], tb)) cfl = true;
        }
        confl[tid] = cfl ? 1 : 0;
        __syncthreads();

        if (tid < 64) {
            int nsel = sh_nsel;
            for (int w0 = 0; w0 < M2 && nsel < MAXB; w0 += 64) {
                int wlim = M2 - w0; if (wlim > 64) wlim = 64;
                bool cfl2 = (tid < wlim) ? (confl[w0 + tid] != 0) : false;
                unsigned long long cmask = __ballot(cfl2);
                int pos = 0;
                while (pos < wlim && nsel < MAXB) {
                    if (!((cmask >> pos) & 1ULL)) {
                        unsigned long long rest = cmask >> pos;
                        int run = rest ? (__ffsll(rest) - 1) : (wlim - pos);
                        if (run > wlim - pos) run = wlim - pos;
                        int avail = MAXB - nsel; if (run > avail) run = avail;
                        int d = (tid - (nsel & 63)) & 63;
                        if (d < run) {
                            int s = nsel + d;
                            int ci = w0 + pos + d;
                            float4 bx = sbx[ci];
                            if (s < 64) sA = bx; else sB = bx;
                            ws_s[s] = __uint_as_float((unsigned)(skeys[ci] >> 32));
                            ws_b[s] = bx;
                        }
                        nsel += run; pos += run;
                    } else {
                        int ci = w0 + pos;
                        float4 bx = sbx[ci];
                        bool sup = (tid < nsel) && iou_gt(sA, bx);
                        if (tid + 64 < nsel) sup = sup || iou_gt(sB, bx);
                        if (__ballot(sup) == 0ULL) {
                            if (tid == (nsel & 63)) { if (nsel < 64) sA = bx; else sB = bx; }
                            if (tid == 0) {
                                ws_s[nsel] = __uint_as_float((unsigned)(skeys[ci] >> 32));
                                ws_b[nsel] = bx;
                            }
                            ++nsel;
                        }
                        ++pos;
                    }
                }
            }
            if (tid == 0) sh_nsel = nsel;
        }
        __syncthreads();
        if (sh_nsel >= MAXB) break;
        for (int i = B + tid; i < NBIN; i += 256) hist[i] = 0;
        hi = B;
        ++round;
        __syncthreads();
    }
}

// Kernel C: per-batch top-100 of 8000: register-cached input, wave-shuffle
// suffix scan, histogram select, rank-sort.
__global__ __launch_bounds__(256) void merge_topk(
    const float* __restrict__ wss, const float4* __restrict__ wsb,
    float* __restrict__ out)
{
    __shared__ int hist[NBIN];
    __shared__ int suf[257];
    __shared__ int wtot[4];
    __shared__ unsigned long long keys[SORT_CAP];
    __shared__ unsigned long long skeys[SORT_CAP];
    __shared__ int sh_B, sh_M;

    int tid = threadIdx.x, b = blockIdx.x;
    int lane = tid & 63, wv = tid >> 6;
    for (int i = tid; i < NBIN / 4; i += 256) ((int4*)hist)[i] = make_int4(0, 0, 0, 0);
    if (tid == 0) sh_M = 0;
    skeys[tid] = 0ULL;
    __syncthreads();

    const float4* w4 = (const float4*)(wss + b * TOT);
    float4 rr[MREG];
#pragma unroll
    for (int k = 0; k < MREG; ++k) {
        int q = tid + k * 256;
        rr[k] = (q < TOTQ) ? w4[q] : make_float4(0, 0, 0, 0);
    }
#pragma unroll
    for (int k = 0; k < MREG; ++k) {
        float4 v = rr[k];
        if (v.x > 0.0f) atomicAdd(&hist[score_bin(v.x)], 1);
        if (v.y > 0.0f) atomicAdd(&hist[score_bin(v.y)], 1);
        if (v.z > 0.0f) atomicAdd(&hist[score_bin(v.z)], 1);
        if (v.w > 0.0f) atomicAdd(&hist[score_bin(v.w)], 1);
    }
    __syncthreads();

    int ps = 0;
#pragma unroll
    for (int u = 0; u < 16; ++u) ps += hist[tid * 16 + u];
    int p = ps;
#pragma unroll
    for (int off = 1; off < 64; off <<= 1) {
        int v = __shfl_down(p, off);
        if (lane + off < 64) p += v;
    }
    if (lane == 0) wtot[wv] = p;
    __syncthreads();
    int add = 0;
    for (int w2 = wv + 1; w2 < 4; ++w2) add += wtot[w2];
    suf[tid] = p + add;
    if (tid == 0) suf[256] = 0;
    __syncthreads();

    int total = suf[0];
    int target = total < MAXB ? total : MAXB;

    if (total > 0) {
        if (suf[tid] >= target && suf[tid + 1] < target) sh_B = tid;
    }
    __syncthreads();
    if (total > 0 && tid == 0) {
        int g = sh_B;
        int running = suf[g + 1];
        int B = g * 16;
        for (int u = 15; u >= 0; --u) {
            running += hist[g * 16 + u];
            if (running >= target) { B = g * 16 + u; break; }
        }
        sh_B = B;
    }
    __syncthreads();
    if (total > 0) {
        int B = sh_B;
#pragma unroll
        for (int k = 0; k < MREG; ++k) {
            int q = tid + k * 256;
            if (q < TOTQ) {
                float4 v = rr[k];
                int ib = q * 4;
                float sv[4] = {v.x, v.y, v.z, v.w};
#pragma unroll
                for (int e = 0; e < 4; ++e) {
                    float s = sv[e];
                    if (s > 0.0f && score_bin(s) >= B) {
                        int pos = atomicAdd(&sh_M, 1);
                        if (pos < SORT_CAP)
                            keys[pos] = ((unsigned long long)__float_as_uint(s) << 32) |
                                        (unsigned)(TOT - 1 - (ib + e));
                    }
                }
            }
        }
    }
    __syncthreads();
    int M = sh_M; if (M > SORT_CAP) M = SORT_CAP;

    unsigned long long mykey = (tid < M) ? keys[tid] : 0ULL;
    int rank = 0;
    for (int j = 0; j < M; ++j) rank += (keys[j] > mykey) ? 1 : 0;
    if (tid < M) skeys[rank] = mykey;
    __syncthreads();

    bool valid = false;
    if (tid < MAXB) {
        unsigned long long g = skeys[tid];
        valid = (g != 0ULL);
        float s = valid ? __uint_as_float((unsigned)(g >> 32)) : 0.0f;
        int f = TOT - 1 - (int)(g & 0xffffffffu);
        float4 bx = make_float4(0, 0, 0, 0);
        float cls = 0.0f;
        if (valid) { bx = wsb[b * TOT + f]; cls = (float)(f / MAXB); }
        ((float4*)out)[b * MAXB + tid] = bx;                          // sel_b
        out[Bn * MAXB * 4 + b * MAXB + tid] = s;                      // sel_s
        out[Bn * MAXB * 5 + b * MAXB + tid] = cls;                    // sel_c
    }
    int nv = __syncthreads_count(valid);
    if (tid == 0) out[Bn * MAXB * 6 + b] = (float)nv;                 // num_valid
}

extern "C" void kernel_launch(void* const* d_in, const int* in_sizes, int n_in,
                              void* d_out, int out_size, void* d_ws, size_t ws_size,
                              hipStream_t stream) {
    const float* boxes = (const float*)d_in[0];
    const float* conf  = (const float*)d_in[1];
    const float* cp    = (const float*)d_in[2];
    float* out = (float*)d_out;

    // workspace layout:
    // [0, 2560)        gcnt[640]
    // [2560, 5120)     tcnt[640]
    // [5376, +2048000) glist[640*400] u64
    // offWss           wss[640*100] f32   (16B-aligned)
    // offWsb           wsb[640*100] float4
    char* ws = (char*)d_ws;
    int* gcnt = (int*)(ws + 0);
    int* tcnt = (int*)(ws + 2560);
    unsigned long long* glist = (unsigned long long*)(ws + 5376);
    size_t offWss = 5376 + (size_t)640 * GCAP * 8;
    offWss = (offWss + 255) & ~(size_t)255;
    size_t offWsb = offWss + (size_t)640 * MAXB * 4;
    offWsb = (offWsb + 255) & ~(size_t)255;
    float* wss = (float*)(ws + offWss);
    float4* wsb = (float4*)(ws + offWsb);

    hipMemsetAsync(d_ws, 0, 5376, stream);   // zero gcnt + tcnt
    collect<<<Bn * ABLK, 256, 0, stream>>>(conf, cp, gcnt, tcnt, glist);
    nms_class<<<Bn * Cn, 256, 0, stream>>>(boxes, conf, cp, gcnt, tcnt, glist,
                                           wss, wsb);
    merge_topk<<<Bn, 256, 0, stream>>>(wss, wsb, out);
}

// Round 8
// 67.373 us; speedup vs baseline: 2.4622x; 1.8426x over previous
//
#include <hip/hip_runtime.h>

#define Bn 8
#define Nn 10647
#define Cn 80
#define MAXB 100
#define SCORE_TH 0.3f
#define BGUESS 0.79f      // cache admission threshold (mean 253/class, sigma ~16)
#define IOU_THR 0.5f
#define NBIN 4096
#define SORT_CAP 256      // slow-path chunk size
#define TARGET 160
#define CH 128            // chunks per batch in collect
#define PCAP 16           // slots per (chunk,class); cell mean ~2, P(>=16)~4e-10
#define LCAP 512          // max cached candidates per class (mean 253, +16 sigma)
#define TRI 192           // triangle/walk chunk (walk needs ~115; 8-sigma margin)
#define TOT (Cn * MAXB)   // 8000
#define TOTQ (TOT / 4)    // 2000
#define MREG 8

// bin index monotone non-decreasing in score; scores in (0.3, 1) -> bins [1, 3688]
__device__ __forceinline__ int score_bin(float s) {
    int v = (int)(__float_as_uint(s) >> 12) - 0x3E999 + 1;
    v = v < 1 ? 1 : v;
    return v > NBIN - 1 ? NBIN - 1 : v;
}

// IoU exactly as reference (symmetric in its two args)
__device__ __forceinline__ bool iou_gt(const float4 s, const float4 c) {
    float x1 = fmaxf(s.x, c.x);
    float y1 = fmaxf(s.y, c.y);
    float x2 = fminf(s.z, c.z);
    float y2 = fminf(s.w, c.w);
    float inter = fmaxf(x2 - x1, 0.0f) * fmaxf(y2 - y1, 0.0f);
    float aS = (s.z - s.x) * (s.w - s.y);
    float aC = (c.z - c.x) * (c.w - c.y);
    return inter / (aS + aC - inter + 1e-9f) > IOU_THR;
}

// Kernel A: one coalesced pass over cp. NO global atomics: each block owns a
// private slot window per class + one packed count word per (chunk,class).
__global__ __launch_bounds__(256) void collect(
    const float* __restrict__ conf, const float* __restrict__ cp,
    int* __restrict__ pcnt, unsigned long long* __restrict__ glist)
{
    __shared__ float lconf[88];
    __shared__ int cnt3[Cn];    // count of s > SCORE_TH
    __shared__ int cnt9[Cn];    // count of s > BGUESS (slot positions)
    int tid = threadIdx.x;
    int b = blockIdx.x / CH;
    int ch = blockIdx.x % CH;

    for (int i = tid; i < Cn; i += 256) { cnt3[i] = 0; cnt9[i] = 0; }

    const int totq = Nn * 20;                       // 212940 float4 per batch
    const int per = (totq + CH - 1) / CH;           // 1664
    int q0 = ch * per;
    int q1 = q0 + per; if (q1 > totq) q1 = totq;
    int n0 = q0 / 20;
    int nspan = (q1 - 1) / 20 - n0 + 1;             // <= 85

    const float* confB = conf + b * Nn;
    for (int i = tid; i < nspan; i += 256) lconf[i] = confB[n0 + i];
    __syncthreads();

    const float4* cp4 = (const float4*)(cp + (size_t)b * Nn * Cn);
    unsigned long long* slotB =
        glist + ((size_t)(b * CH + ch) * Cn) * PCAP;

    for (int q = q0 + tid; q < q1; q += 256) {      // ~6.5 iters
        float4 v = cp4[q];
        int n = q / 20;
        int c0 = (q % 20) * 4;
        float cf = lconf[n - n0];
        float sv[4] = {v.x, v.y, v.z, v.w};
#pragma unroll
        for (int e = 0; e < 4; ++e) {
            float s = cf * sv[e];
            if (s > SCORE_TH) {
                atomicAdd(&cnt3[c0 + e], 1);
                if (s > BGUESS) {
                    int pos = atomicAdd(&cnt9[c0 + e], 1);   // LDS only
                    if (pos < PCAP)
                        slotB[(c0 + e) * PCAP + pos] =
                            ((unsigned long long)__float_as_uint(s) << 32) |
                            (unsigned)(Nn - 1 - n);
                }
            }
        }
    }
    __syncthreads();
    // packed counts: lo16 = total s>0.3, hi16 = cached s>0.79 (may exceed PCAP
    // to signal overflow). Non-atomic — this block owns these 80 cells.
    int* pB = pcnt + (size_t)(b * CH + ch) * Cn;
    for (int c = tid; c < Cn; c += 256)
        pB[c] = (cnt3[c] & 0xFFFF) | (cnt9[c] << 16);
}

// Kernel B: per-(b,c) NMS from the slotted cache. Compact -> 2-key rank-sort
// -> triangle over first TRI -> run-append walk -> exact ballot remainder;
// exact slow-path full redo if cache insufficient (never in practice).
__global__ __launch_bounds__(256) void nms_class(
    const float* __restrict__ boxes, const float* __restrict__ conf,
    const float* __restrict__ cp,
    const int* __restrict__ pcnt, const unsigned long long* __restrict__ glist,
    float* __restrict__ wss, float4* __restrict__ wsb)
{
    __shared__ unsigned long long keys[LCAP];    // 4 KB
    __shared__ unsigned long long skeys[LCAP];   // 4 KB
    __shared__ float4 sbx[LCAP];                 // 8 KB
    __shared__ unsigned char confl[LCAP];
    __shared__ int hist[NBIN];                   // 16 KB (slow path only)
    __shared__ int suf[257];
    __shared__ int wtot[4];
    __shared__ int chc[CH];
    __shared__ int sh_cnt, sh_tot, sh_ovf, sh_pos;
    __shared__ int sh_B, sh_M, sh_nsel;

    int tid = threadIdx.x;
    int lane = tid & 63, wv = tid >> 6;
    int bc = blockIdx.x;
    int b = bc / Cn, c = bc % Cn;

    if (tid == 0) { sh_cnt = 0; sh_tot = 0; sh_ovf = 0; sh_pos = 0; sh_nsel = 0; }
    __syncthreads();

    if (tid < CH) {
        int p = pcnt[(size_t)(b * CH + tid) * Cn + c];
        int c9 = p >> 16;
        chc[tid] = c9;
        atomicAdd(&sh_tot, p & 0xFFFF);
        atomicAdd(&sh_cnt, c9);
        if (c9 > PCAP) atomicOr(&sh_ovf, 1);
    }
    float* ws_s = wss + bc * MAXB;
    float4* ws_b = wsb + bc * MAXB;
    for (int i = tid; i < MAXB; i += 256) ws_s[i] = 0.0f;
    __syncthreads();

    int cnt = sh_cnt;
    int tot = sh_tot;
    bool fast = (!sh_ovf) && (cnt <= LCAP);
    int M = fast ? cnt : 0;

    // compact valid slots into keys[] (order arbitrary; rank-sort fixes it)
    if (fast) {
        const unsigned long long* slotC = glist + (size_t)(b * CH) * Cn * PCAP
                                                + (size_t)c * PCAP;
        for (int i = tid; i < CH * PCAP; i += 256) {     // 8 iters
            int ch = i >> 4, j = i & (PCAP - 1);
            if (j < chc[ch]) {
                int pos = atomicAdd(&sh_pos, 1);
                keys[pos] = slotC[(size_t)ch * Cn * PCAP + j];
            }
        }
    }
    __syncthreads();

    const float4* boxesB = (const float4*)boxes + (size_t)b * Nn;

    // ---------- fast path ----------
    {
        unsigned long long k0 = keys[tid], k1 = keys[tid + 256];
        float4 b0 = make_float4(0, 0, 0, 0), b1 = make_float4(0, 0, 0, 0);
        if (tid < M) b0 = boxesB[Nn - 1 - (int)(k0 & 0xffffffffu)];
        if (tid + 256 < M) b1 = boxesB[Nn - 1 - (int)(k1 & 0xffffffffu)];
        // rank-sort (keys unique; uniform j-loop -> LDS broadcast, no barriers)
        int r0 = 0, r1 = 0;
        for (int j = 0; j < M; ++j) {
            unsigned long long kk = keys[j];
            if (kk > k0) ++r0;
            if (kk > k1) ++r1;
        }
        if (tid < M) { skeys[r0] = k0; sbx[r0] = b0; }
        if (tid + 256 < M) { skeys[r1] = k1; sbx[r1] = b1; }
        __syncthreads();

        // triangle conflict pass over first T sorted only; 2-way unrolled ILP
        int T = M < TRI ? M : TRI;
        bool cf0 = false;
        if (tid < T) {
            float4 tb = sbx[tid];
            bool fa = false, fb = false;
            int i = 0;
            for (; i + 1 < tid; i += 2) {
                float4 ba = sbx[i], bb2 = sbx[i + 1];   // independent loads
                fa = fa || iou_gt(ba, tb);
                fb = fb || iou_gt(bb2, tb);
            }
            if (i < tid) fa = fa || iou_gt(sbx[i], tb);
            cf0 = fa || fb;
        }
        confl[tid] = cf0 ? 1 : 0;
        __syncthreads();

        // walk: wave 0; chunk 0 = first T with run-append; remainder ballot-only
        if (tid < 64) {
            float4 sA = make_float4(0, 0, 0, 0), sB = make_float4(0, 0, 0, 0);
            int nsel = 0;
            for (int w0 = 0; w0 < T && nsel < MAXB; w0 += 64) {
                int wlim = T - w0; if (wlim > 64) wlim = 64;
                bool cfl = (tid < wlim) ? (confl[w0 + tid] != 0) : false;
                unsigned long long cmask = __ballot(cfl);
                int pos = 0;
                while (pos < wlim && nsel < MAXB) {
                    if (!((cmask >> pos) & 1ULL)) {
                        unsigned long long rest = cmask >> pos;
                        int run = rest ? (__ffsll(rest) - 1) : (wlim - pos);
                        if (run > wlim - pos) run = wlim - pos;
                        int avail = MAXB - nsel; if (run > avail) run = avail;
                        int d = (tid - (nsel & 63)) & 63;
                        if (d < run) {
                            int s = nsel + d;
                            int ci = w0 + pos + d;
                            float4 bx = sbx[ci];
                            if (s < 64) sA = bx; else sB = bx;
                            ws_s[s] = __uint_as_float((unsigned)(skeys[ci] >> 32));
                            ws_b[s] = bx;
                        }
                        nsel += run; pos += run;
                    } else {
                        int ci = w0 + pos;
                        float4 bx = sbx[ci];
                        bool sup = (tid < nsel) && iou_gt(sA, bx);
                        if (tid + 64 < nsel) sup = sup || iou_gt(sB, bx);
                        if (__ballot(sup) == 0ULL) {
                            if (tid == (nsel & 63)) { if (nsel < 64) sA = bx; else sB = bx; }
                            if (tid == 0) {
                                ws_s[nsel] = __uint_as_float((unsigned)(skeys[ci] >> 32));
                                ws_b[nsel] = bx;
                            }
                            ++nsel;
                        }
                        ++pos;
                    }
                }
            }
            // remainder [T, M): exact per-candidate ballot (essentially never)
            for (int ci = T; ci < M && nsel < MAXB; ++ci) {
                float4 bx = sbx[ci];
                bool sup = (tid < nsel) && iou_gt(sA, bx);
                if (tid + 64 < nsel) sup = sup || iou_gt(sB, bx);
                if (__ballot(sup) == 0ULL) {
                    if (tid == (nsel & 63)) { if (nsel < 64) sA = bx; else sB = bx; }
                    if (tid == 0) {
                        ws_s[nsel] = __uint_as_float((unsigned)(skeys[ci] >> 32));
                        ws_b[nsel] = bx;
                    }
                    ++nsel;
                }
            }
            if (tid == 0) sh_nsel = nsel;
        }
        __syncthreads();
    }

    // done iff walk filled MAXB, or every existing candidate was cached+processed
    bool needSlow = (!fast) || !((sh_nsel >= MAXB) || (cnt == tot));
    if (!needSlow) return;

    // ---------- slow path: exact full redo (never taken in practice) ----------
    for (int i = tid; i < MAXB; i += 256) ws_s[i] = 0.0f;
    for (int i = tid; i < NBIN / 4; i += 256) ((int4*)hist)[i] = make_int4(0, 0, 0, 0);
    if (tid == 0) sh_nsel = 0;
    __syncthreads();

    const float* confB = conf + b * Nn;
    const float* cpB = cp + (size_t)b * Nn * Cn + c;
    for (int n = tid; n < Nn; n += 256) {
        float s = confB[n] * cpB[(size_t)n * Cn];
        if (s > SCORE_TH) atomicAdd(&hist[score_bin(s)], 1);
    }
    __syncthreads();

    float4 sA = make_float4(0, 0, 0, 0), sB = make_float4(0, 0, 0, 0);
    int hi = NBIN;
    int round = 0;

    while (true) {
        int ps = 0;
#pragma unroll
        for (int u = 0; u < 16; ++u) ps += hist[tid * 16 + u];
        int p = ps;
#pragma unroll
        for (int off = 1; off < 64; off <<= 1) {
            int v = __shfl_down(p, off);
            if (lane + off < 64) p += v;
        }
        if (lane == 0) wtot[wv] = p;
        __syncthreads();
        int add = 0;
        for (int w2 = wv + 1; w2 < 4; ++w2) add += wtot[w2];
        suf[tid] = p + add;
        if (tid == 0) suf[256] = 0;
        __syncthreads();

        int total = suf[0];
        if (total == 0) break;

        int target = total < TARGET ? total : TARGET;
        if (suf[tid] >= target && suf[tid + 1] < target) sh_B = tid;
        if (tid == 0) sh_M = 0;
        __syncthreads();
        if (tid == 0) {
            int g = sh_B;
            int running = suf[g + 1];
            int B = g * 16;
            for (int u = 15; u >= 0; --u) {
                running += hist[g * 16 + u];
                if (running >= target) { B = g * 16 + u; break; }
            }
            sh_B = B;
        }
        __syncthreads();
        int B = sh_B;

        for (int n = tid; n < Nn; n += 256) {
            float s = confB[n] * cpB[(size_t)n * Cn];
            if (s > SCORE_TH) {
                int bin = score_bin(s);
                if (bin >= B && bin < hi) {
                    int pos2 = atomicAdd(&sh_M, 1);
                    if (pos2 < SORT_CAP)
                        keys[pos2] = ((unsigned long long)__float_as_uint(s) << 32) |
                                     (unsigned)(Nn - 1 - n);
                }
            }
        }
        __syncthreads();
        int M2 = sh_M; if (M2 > SORT_CAP) M2 = SORT_CAP;

        unsigned long long mykey = (tid < M2) ? keys[tid] : 0ULL;
        float4 mybox = make_float4(0, 0, 0, 0);
        if (tid < M2) mybox = boxesB[Nn - 1 - (int)(mykey & 0xffffffffu)];
        int rank = 0;
        for (int j = 0; j < M2; ++j) rank += (keys[j] > mykey) ? 1 : 0;
        if (tid < M2) { skeys[rank] = mykey; sbx[rank] = mybox; }
        __syncthreads();

        bool cfl = (round > 0);
        if (round == 0 && tid < M2) {
            float4 tb = sbx[tid];
            for (int i = 0; i < tid; ++i)
                if (iou_gt(sbx[i], tb)) cfl = true;
        }
        confl[tid] = cfl ? 1 : 0;
        __syncthreads();

        if (tid < 64) {
            int nsel = sh_nsel;
            for (int w0 = 0; w0 < M2 && nsel < MAXB; w0 += 64) {
                int wlim = M2 - w0; if (wlim > 64) wlim = 64;
                bool cfl2 = (tid < wlim) ? (confl[w0 + tid] != 0) : false;
                unsigned long long cmask = __ballot(cfl2);
                int pos = 0;
                while (pos < wlim && nsel < MAXB) {
                    if (!((cmask >> pos) & 1ULL)) {
                        unsigned long long rest = cmask >> pos;
                        int run = rest ? (__ffsll(rest) - 1) : (wlim - pos);
                        if (run > wlim - pos) run = wlim - pos;
                        int avail = MAXB - nsel; if (run > avail) run = avail;
                        int d = (tid - (nsel & 63)) & 63;
                        if (d < run) {
                            int s = nsel + d;
                            int ci = w0 + pos + d;
                            float4 bx = sbx[ci];
                            if (s < 64) sA = bx; else sB = bx;
                            ws_s[s] = __uint_as_float((unsigned)(skeys[ci] >> 32));
                            ws_b[s] = bx;
                        }
                        nsel += run; pos += run;
                    } else {
                        int ci = w0 + pos;
                        float4 bx = sbx[ci];
                        bool sup = (tid < nsel) && iou_gt(sA, bx);
                        if (tid + 64 < nsel) sup = sup || iou_gt(sB, bx);
                        if (__ballot(sup) == 0ULL) {
                            if (tid == (nsel & 63)) { if (nsel < 64) sA = bx; else sB = bx; }
                            if (tid == 0) {
                                ws_s[nsel] = __uint_as_float((unsigned)(skeys[ci] >> 32));
                                ws_b[nsel] = bx;
                            }
                            ++nsel;
                        }
                        ++pos;
                    }
                }
            }
            if (tid == 0) sh_nsel = nsel;
        }
        __syncthreads();
        if (sh_nsel >= MAXB) break;
        for (int i = B + tid; i < NBIN; i += 256) hist[i] = 0;
        hi = B;
        ++round;
        __syncthreads();
    }
}

// Kernel C: per-batch top-100 of 8000: register-cached input, wave-shuffle
// suffix scan, histogram select, rank-sort.
__global__ __launch_bounds__(256) void merge_topk(
    const float* __restrict__ wss, const float4* __restrict__ wsb,
    float* __restrict__ out)
{
    __shared__ int hist[NBIN];
    __shared__ int suf[257];
    __shared__ int wtot[4];
    __shared__ unsigned long long keys[SORT_CAP];
    __shared__ unsigned long long skeys[SORT_CAP];
    __shared__ int sh_B, sh_M;

    int tid = threadIdx.x, b = blockIdx.x;
    int lane = tid & 63, wv = tid >> 6;
    for (int i = tid; i < NBIN / 4; i += 256) ((int4*)hist)[i] = make_int4(0, 0, 0, 0);
    if (tid == 0) sh_M = 0;
    skeys[tid] = 0ULL;
    __syncthreads();

    const float4* w4 = (const float4*)(wss + b * TOT);
    float4 rr[MREG];
#pragma unroll
    for (int k = 0; k < MREG; ++k) {
        int q = tid + k * 256;
        rr[k] = (q < TOTQ) ? w4[q] : make_float4(0, 0, 0, 0);
    }
#pragma unroll
    for (int k = 0; k < MREG; ++k) {
        float4 v = rr[k];
        if (v.x > 0.0f) atomicAdd(&hist[score_bin(v.x)], 1);
        if (v.y > 0.0f) atomicAdd(&hist[score_bin(v.y)], 1);
        if (v.z > 0.0f) atomicAdd(&hist[score_bin(v.z)], 1);
        if (v.w > 0.0f) atomicAdd(&hist[score_bin(v.w)], 1);
    }
    __syncthreads();

    int ps = 0;
#pragma unroll
    for (int u = 0; u < 16; ++u) ps += hist[tid * 16 + u];
    int p = ps;
#pragma unroll
    for (int off = 1; off < 64; off <<= 1) {
        int v = __shfl_down(p, off);
        if (lane + off < 64) p += v;
    }
    if (lane == 0) wtot[wv] = p;
    __syncthreads();
    int add = 0;
    for (int w2 = wv + 1; w2 < 4; ++w2) add += wtot[w2];
    suf[tid] = p + add;
    if (tid == 0) suf[256] = 0;
    __syncthreads();

    int total = suf[0];
    int target = total < MAXB ? total : MAXB;

    if (total > 0) {
        if (suf[tid] >= target && suf[tid + 1] < target) sh_B = tid;
    }
    __syncthreads();
    if (total > 0 && tid == 0) {
        int g = sh_B;
        int running = suf[g + 1];
        int B = g * 16;
        for (int u = 15; u >= 0; --u) {
            running += hist[g * 16 + u];
            if (running >= target) { B = g * 16 + u; break; }
        }
        sh_B = B;
    }
    __syncthreads();
    if (total > 0) {
        int B = sh_B;
#pragma unroll
        for (int k = 0; k < MREG; ++k) {
            int q = tid + k * 256;
            if (q < TOTQ) {
                float4 v = rr[k];
                int ib = q * 4;
                float sv[4] = {v.x, v.y, v.z, v.w};
#pragma unroll
                for (int e = 0; e < 4; ++e) {
                    float s = sv[e];
                    if (s > 0.0f && score_bin(s) >= B) {
                        int pos = atomicAdd(&sh_M, 1);
                        if (pos < SORT_CAP)
                            keys[pos] = ((unsigned long long)__float_as_uint(s) << 32) |
                                        (unsigned)(TOT - 1 - (ib + e));
                    }
                }
            }
        }
    }
    __syncthreads();
    int M = sh_M; if (M > SORT_CAP) M = SORT_CAP;

    unsigned long long mykey = (tid < M) ? keys[tid] : 0ULL;
    int rank = 0;
    for (int j = 0; j < M; ++j) rank += (keys[j] > mykey) ? 1 : 0;
    if (tid < M) skeys[rank] = mykey;
    __syncthreads();

    bool valid = false;
    if (tid < MAXB) {
        unsigned long long g = skeys[tid];
        valid = (g != 0ULL);
        float s = valid ? __uint_as_float((unsigned)(g >> 32)) : 0.0f;
        int f = TOT - 1 - (int)(g & 0xffffffffu);
        float4 bx = make_float4(0, 0, 0, 0);
        float cls = 0.0f;
        if (valid) { bx = wsb[b * TOT + f]; cls = (float)(f / MAXB); }
        ((float4*)out)[b * MAXB + tid] = bx;                          // sel_b
        out[Bn * MAXB * 4 + b * MAXB + tid] = s;                      // sel_s
        out[Bn * MAXB * 5 + b * MAXB + tid] = cls;                    // sel_c
    }
    int nv = __syncthreads_count(valid);
    if (tid == 0) out[Bn * MAXB * 6 + b] = (float)nv;                 // num_valid
}

extern "C" void kernel_launch(void* const* d_in, const int* in_sizes, int n_in,
                              void* d_out, int out_size, void* d_ws, size_t ws_size,
                              hipStream_t stream) {
    const float* boxes = (const float*)d_in[0];
    const float* conf  = (const float*)d_in[1];
    const float* cp    = (const float*)d_in[2];
    float* out = (float*)d_out;

    // workspace layout (no pre-zeroing needed — pcnt fully rewritten each run):
    // [0, 327680)            pcnt[B*CH*Cn] packed counts
    // [327680, +10485760)    glist slots [B*CH*Cn*PCAP] u64
    // offWss                 wss[640*100] f32
    // offWsb                 wsb[640*100] float4
    char* ws = (char*)d_ws;
    int* pcnt = (int*)(ws + 0);
    unsigned long long* glist = (unsigned long long*)(ws + 327680);
    size_t offWss = 327680 + (size_t)Bn * CH * Cn * PCAP * 8;   // 10,813,440
    float* wss = (float*)(ws + offWss);
    size_t offWsb = offWss + (size_t)640 * MAXB * 4;            // 11,069,440
    float4* wsb = (float4*)(ws + offWsb);

    collect<<<Bn * CH, 256, 0, stream>>>(conf, cp, pcnt, glist);
    nms_class<<<Bn * Cn, 256, 0, stream>>>(boxes, conf, cp, pcnt, glist, wss, wsb);
    merge_topk<<<Bn, 256, 0, stream>>>(wss, wsb, out);
}

// Round 9
// 65.716 us; speedup vs baseline: 2.5243x; 1.0252x over previous
//
#include <hip/hip_runtime.h>

#define Bn 8
#define Nn 10647
#define Cn 80
#define MAXB 100
#define SCORE_TH 0.3f
#define BGUESS 0.82f      // cache admission threshold (mean ~184/class, sigma ~13.5)
#define IOU_THR 0.5f
#define NBIN 4096         // merge_topk histogram
#define NB2 1024          // slow-path histogram (4 KB)
#define SORT_CAP 256      // slow-path chunk size
#define TARGET 160
#define CH 128            // chunks per batch in collect
#define PCAP 16           // slots per (chunk,class); cell mean ~1.4
#define LCAP 512
#define TOT (Cn * MAXB)   // 8000
#define TOTQ (TOT / 4)    // 2000
#define MREG 8

// 4096-bin map for merge_topk; scores in (0.3, 1) -> bins [1, 3688]
__device__ __forceinline__ int score_bin(float s) {
    int v = (int)(__float_as_uint(s) >> 12) - 0x3E999 + 1;
    v = v < 1 ? 1 : v;
    return v > NBIN - 1 ? NBIN - 1 : v;
}
// 1024-bin map for slow path; scores in (0.3, 1) -> bins [1, 923]
__device__ __forceinline__ int score_bin2(float s) {
    int v = (int)(__float_as_uint(s) >> 14) - 0xFA66 + 1;
    v = v < 1 ? 1 : v;
    return v > NB2 - 1 ? NB2 - 1 : v;
}

// Division-free IoU decision: inter/(aS+aC-inter+1e-9) > 0.5
__device__ __forceinline__ bool iou_gt(const float4 s, const float4 c) {
    float x1 = fmaxf(s.x, c.x), y1 = fmaxf(s.y, c.y);
    float x2 = fminf(s.z, c.z), y2 = fminf(s.w, c.w);
    float inter = fmaxf(x2 - x1, 0.0f) * fmaxf(y2 - y1, 0.0f);
    float aS = (s.z - s.x) * (s.w - s.y);
    float aC = (c.z - c.x) * (c.w - c.y);
    return inter > IOU_THR * (aS + aC - inter + 1e-9f);
}

// Kernel A: one coalesced pass over cp. No global atomics; layouts transposed
// to [b][c][ch] so nms_class reads contiguously.
__global__ __launch_bounds__(256) void collect(
    const float* __restrict__ conf, const float* __restrict__ cp,
    int* __restrict__ pcnt, unsigned long long* __restrict__ glist)
{
    __shared__ float lconf[88];
    __shared__ int cnt3[Cn];    // count of s > SCORE_TH
    __shared__ int cnt9[Cn];    // count of s > BGUESS (slot positions)
    int tid = threadIdx.x;
    int b = blockIdx.x / CH;
    int ch = blockIdx.x % CH;

    for (int i = tid; i < Cn; i += 256) { cnt3[i] = 0; cnt9[i] = 0; }

    const int totq = Nn * 20;                       // 212940 float4 per batch
    const int per = (totq + CH - 1) / CH;           // 1664
    int q0 = ch * per;
    int q1 = q0 + per; if (q1 > totq) q1 = totq;
    int n0 = q0 / 20;
    int nspan = (q1 - 1) / 20 - n0 + 1;             // <= 85

    const float* confB = conf + b * Nn;
    for (int i = tid; i < nspan; i += 256) lconf[i] = confB[n0 + i];
    __syncthreads();

    const float4* cp4 = (const float4*)(cp + (size_t)b * Nn * Cn);

    for (int q = q0 + tid; q < q1; q += 256) {      // ~6.5 iters
        float4 v = cp4[q];
        int n = q / 20;
        int c0 = (q % 20) * 4;
        float cf = lconf[n - n0];
        float sv[4] = {v.x, v.y, v.z, v.w};
#pragma unroll
        for (int e = 0; e < 4; ++e) {
            float s = cf * sv[e];
            if (s > SCORE_TH) {
                atomicAdd(&cnt3[c0 + e], 1);
                if (s > BGUESS) {
                    int pos = atomicAdd(&cnt9[c0 + e], 1);   // LDS only
                    if (pos < PCAP)
                        glist[((size_t)(b * Cn + c0 + e) * CH + ch) * PCAP + pos] =
                            ((unsigned long long)__float_as_uint(s) << 32) |
                            (unsigned)(Nn - 1 - n);
                }
            }
        }
    }
    __syncthreads();
    // packed counts: lo16 = total s>0.3, hi16 = cached count (may exceed PCAP
    // to signal overflow). Non-atomic single-owner writes, [b][c][ch] layout.
    for (int c = tid; c < Cn; c += 256)
        pcnt[(size_t)(b * Cn + c) * CH + ch] = (cnt3[c] & 0xFFFF) | (cnt9[c] << 16);
}

// Kernel B: per-(b,c) NMS. Contiguous count/slot reads, scan compaction,
// FUSED rank+conflict single pass, run-append walk over full M.
// Exact slow-path full redo (never taken in practice) if cache insufficient.
__global__ __launch_bounds__(256) void nms_class(
    const float* __restrict__ boxes, const float* __restrict__ conf,
    const float* __restrict__ cp,
    const int* __restrict__ pcnt, const unsigned long long* __restrict__ glist,
    float* __restrict__ wss, float4* __restrict__ wsb)
{
    __shared__ unsigned long long keys[LCAP];    // 4 KB (compact order)
    __shared__ float4 bxu[LCAP];                 // 8 KB (compact-order boxes)
    __shared__ float ssc[LCAP];                  // 2 KB (sorted scores)
    __shared__ float4 sbx[LCAP];                 // 8 KB (sorted boxes)
    __shared__ unsigned char confl[LCAP];
    __shared__ int chc[CH], chOff[CH], pscan[CH];
    __shared__ int hist2[NB2];                   // 4 KB (slow path only)
    __shared__ int suf[257];
    __shared__ int wtot[4];
    __shared__ int sh_tot, sh_ovf, sh_B, sh_M, sh_nsel;

    int tid = threadIdx.x;
    int lane = tid & 63, wv = tid >> 6;
    int bc = blockIdx.x;
    int b = bc / Cn, c = bc % Cn;

    if (tid == 0) { sh_tot = 0; sh_ovf = 0; sh_nsel = 0; }
    __syncthreads();

    // counts: 128 contiguous ints; shuffle scan for deterministic slot offsets
    if (tid < CH) {
        int p = pcnt[(size_t)(b * Cn + c) * CH + tid];
        int c9 = p >> 16;
        if (c9 > PCAP) { atomicOr(&sh_ovf, 1); c9 = PCAP; }
        chc[tid] = c9;
        atomicAdd(&sh_tot, p & 0xFFFF);
        int incl = c9;
#pragma unroll
        for (int off = 1; off < 64; off <<= 1) {
            int o = __shfl_up(incl, off);
            if (lane >= off) incl += o;
        }
        pscan[tid] = incl;
    }
    float* ws_s = wss + bc * MAXB;
    float4* ws_b = wsb + bc * MAXB;
    for (int i = tid; i < MAXB; i += 256) ws_s[i] = 0.0f;
    __syncthreads();
    if (tid < CH) {
        int base = (tid >= 64) ? pscan[63] : 0;
        chOff[tid] = base + pscan[tid] - chc[tid];
    }
    __syncthreads();

    int cnt = pscan[63] + pscan[127];   // total cached (clamped)
    int tot = sh_tot;
    bool fast = (!sh_ovf) && (cnt <= LCAP);
    int M = fast ? cnt : 0;

    // compaction: fully contiguous slot reads, scan-derived positions
    if (fast) {
        const unsigned long long* slotC = glist + (size_t)(b * Cn + c) * CH * PCAP;
        for (int i = tid; i < CH * PCAP; i += 256) {     // 8 coalesced iters
            int ch = i >> 4, j = i & (PCAP - 1);
            if (j < chc[ch]) keys[chOff[ch] + j] = slotC[i];
        }
    }
    __syncthreads();

    const float4* boxesB = (const float4*)boxes + (size_t)b * Nn;

    // own candidate(s) + scattered box gather into LDS (compact order)
    unsigned long long k0 = 0, k1 = 0;
    float4 b0 = make_float4(0, 0, 0, 0), b1 = make_float4(0, 0, 0, 0);
    if (tid < M) { k0 = keys[tid]; b0 = boxesB[Nn - 1 - (int)(k0 & 0xffffffffu)]; }
    bxu[tid] = b0;
    if (M > 256) {
        if (tid + 256 < M) { k1 = keys[tid + 256]; b1 = boxesB[Nn - 1 - (int)(k1 & 0xffffffffu)]; }
        bxu[tid + 256] = b1;
    }
    __syncthreads();

    // FUSED rank + conflict: one uniform pass over all M (LDS broadcasts)
    int r0 = 0, r1 = 0;
    bool cf0 = false, cf1 = false;
    if (M <= 256) {
#pragma unroll 2
        for (int j = 0; j < M; ++j) {
            unsigned long long kk = keys[j];
            float4 bj = bxu[j];
            bool gt = kk > k0;
            r0 += gt ? 1 : 0;
            cf0 = cf0 || (gt && iou_gt(bj, b0));
        }
    } else {
#pragma unroll 2
        for (int j = 0; j < M; ++j) {
            unsigned long long kk = keys[j];
            float4 bj = bxu[j];
            bool g0 = kk > k0, g1 = kk > k1;
            r0 += g0 ? 1 : 0;
            r1 += g1 ? 1 : 0;
            cf0 = cf0 || (g0 && iou_gt(bj, b0));
            cf1 = cf1 || (g1 && iou_gt(bj, b1));
        }
    }
    if (tid < M) {
        ssc[r0] = __uint_as_float((unsigned)(k0 >> 32));
        sbx[r0] = b0; confl[r0] = cf0 ? 1 : 0;
    }
    if (M > 256 && tid + 256 < M) {
        ssc[r1] = __uint_as_float((unsigned)(k1 >> 32));
        sbx[r1] = b1; confl[r1] = cf1 ? 1 : 0;
    }
    __syncthreads();

    // walk: wave 0; conflict-free -> parallel run-append, else exact ballot
    if (tid < 64) {
        float4 sA = make_float4(0, 0, 0, 0), sB = make_float4(0, 0, 0, 0);
        int nsel = 0;
        for (int w0 = 0; w0 < M && nsel < MAXB; w0 += 64) {
            int wlim = M - w0; if (wlim > 64) wlim = 64;
            bool cfl = (tid < wlim) ? (confl[w0 + tid] != 0) : false;
            unsigned long long cmask = __ballot(cfl);
            int pos = 0;
            while (pos < wlim && nsel < MAXB) {
                if (!((cmask >> pos) & 1ULL)) {
                    unsigned long long rest = cmask >> pos;
                    int run = rest ? (__ffsll(rest) - 1) : (wlim - pos);
                    if (run > wlim - pos) run = wlim - pos;
                    int avail = MAXB - nsel; if (run > avail) run = avail;
                    int d = (tid - (nsel & 63)) & 63;
                    if (d < run) {
                        int s = nsel + d;
                        int ci = w0 + pos + d;
                        float4 bx = sbx[ci];
                        if (s < 64) sA = bx; else sB = bx;
                        ws_s[s] = ssc[ci]; ws_b[s] = bx;
                    }
                    nsel += run; pos += run;
                } else {
                    int ci = w0 + pos;
                    float4 bx = sbx[ci];
                    bool sup = (tid < nsel) && iou_gt(sA, bx);
                    if (tid + 64 < nsel) sup = sup || iou_gt(sB, bx);
                    if (__ballot(sup) == 0ULL) {
                        if (tid == (nsel & 63)) { if (nsel < 64) sA = bx; else sB = bx; }
                        if (tid == 0) { ws_s[nsel] = ssc[ci]; ws_b[nsel] = bx; }
                        ++nsel;
                    }
                    ++pos;
                }
            }
        }
        if (tid == 0) sh_nsel = nsel;
    }
    __syncthreads();

    bool needSlow = (!fast) || !((sh_nsel >= MAXB) || (cnt == tot));
    if (!needSlow) return;

    // ---------- slow path: exact full redo (never taken in practice) ----------
    for (int i = tid; i < MAXB; i += 256) ws_s[i] = 0.0f;
    for (int i = tid; i < NB2 / 4; i += 256) ((int4*)hist2)[i] = make_int4(0, 0, 0, 0);
    if (tid == 0) sh_nsel = 0;
    __syncthreads();

    const float* confB = conf + b * Nn;
    const float* cpB = cp + (size_t)b * Nn * Cn + c;
    for (int n = tid; n < Nn; n += 256) {
        float s = confB[n] * cpB[(size_t)n * Cn];
        if (s > SCORE_TH) atomicAdd(&hist2[score_bin2(s)], 1);
    }
    __syncthreads();

    float4 sA = make_float4(0, 0, 0, 0), sB = make_float4(0, 0, 0, 0);
    int hi = NB2;
    int round = 0;

    while (true) {
        int ps = 0;
#pragma unroll
        for (int u = 0; u < 4; ++u) ps += hist2[tid * 4 + u];
        int p = ps;
#pragma unroll
        for (int off = 1; off < 64; off <<= 1) {
            int v = __shfl_down(p, off);
            if (lane + off < 64) p += v;
        }
        if (lane == 0) wtot[wv] = p;
        __syncthreads();
        int add = 0;
        for (int w2 = wv + 1; w2 < 4; ++w2) add += wtot[w2];
        suf[tid] = p + add;
        if (tid == 0) suf[256] = 0;
        __syncthreads();

        int total = suf[0];
        if (total == 0) break;

        int target = total < TARGET ? total : TARGET;
        if (suf[tid] >= target && suf[tid + 1] < target) sh_B = tid;
        if (tid == 0) sh_M = 0;
        __syncthreads();
        if (tid == 0) {
            int g = sh_B;
            int running = suf[g + 1];
            int B = g * 4;
            for (int u = 3; u >= 0; --u) {
                running += hist2[g * 4 + u];
                if (running >= target) { B = g * 4 + u; break; }
            }
            sh_B = B;   // take ALL of boundary bin -> exact cross-round ordering
        }
        __syncthreads();
        int B = sh_B;

        for (int n = tid; n < Nn; n += 256) {
            float s = confB[n] * cpB[(size_t)n * Cn];
            if (s > SCORE_TH) {
                int bin = score_bin2(s);
                if (bin >= B && bin < hi) {
                    int pos2 = atomicAdd(&sh_M, 1);
                    if (pos2 < SORT_CAP)
                        keys[pos2] = ((unsigned long long)__float_as_uint(s) << 32) |
                                     (unsigned)(Nn - 1 - n);
                }
            }
        }
        __syncthreads();
        int M2 = sh_M; if (M2 > SORT_CAP) M2 = SORT_CAP;

        unsigned long long mk = (tid < M2) ? keys[tid] : 0ULL;
        float4 mb = make_float4(0, 0, 0, 0);
        if (tid < M2) mb = boxesB[Nn - 1 - (int)(mk & 0xffffffffu)];
        bxu[tid] = mb;
        __syncthreads();

        int rank = 0;
        bool cfl = (round > 0);   // multi-round: force exact ballot path
        for (int j = 0; j < M2; ++j) {
            unsigned long long kk = keys[j];
            float4 bj = bxu[j];
            bool gt = kk > mk;
            rank += gt ? 1 : 0;
            if (round == 0) cfl = cfl || (gt && iou_gt(bj, mb));
        }
        if (tid < M2) {
            ssc[rank] = __uint_as_float((unsigned)(mk >> 32));
            sbx[rank] = mb; confl[rank] = cfl ? 1 : 0;
        }
        __syncthreads();

        if (tid < 64) {
            int nsel = sh_nsel;
            for (int w0 = 0; w0 < M2 && nsel < MAXB; w0 += 64) {
                int wlim = M2 - w0; if (wlim > 64) wlim = 64;
                bool cfl2 = (tid < wlim) ? (confl[w0 + tid] != 0) : false;
                unsigned long long cmask = __ballot(cfl2);
                int pos = 0;
                while (pos < wlim && nsel < MAXB) {
                    if (!((cmask >> pos) & 1ULL)) {
                        unsigned long long rest = cmask >> pos;
                        int run = rest ? (__ffsll(rest) - 1) : (wlim - pos);
                        if (run > wlim - pos) run = wlim - pos;
                        int avail = MAXB - nsel; if (run > avail) run = avail;
                        int d = (tid - (nsel & 63)) & 63;
                        if (d < run) {
                            int s = nsel + d;
                            int ci = w0 + pos + d;
                            float4 bx = sbx[ci];
                            if (s < 64) sA = bx; else sB = bx;
                            ws_s[s] = ssc[ci]; ws_b[s] = bx;
                        }
                        nsel += run; pos += run;
                    } else {
                        int ci = w0 + pos;
                        float4 bx = sbx[ci];
                        bool sup = (tid < nsel) && iou_gt(sA, bx);
                        if (tid + 64 < nsel) sup = sup || iou_gt(sB, bx);
                        if (__ballot(sup) == 0ULL) {
                            if (tid == (nsel & 63)) { if (nsel < 64) sA = bx; else sB = bx; }
                            if (tid == 0) { ws_s[nsel] = ssc[ci]; ws_b[nsel] = bx; }
                            ++nsel;
                        }
                        ++pos;
                    }
                }
            }
            if (tid == 0) sh_nsel = nsel;
        }
        __syncthreads();
        if (sh_nsel >= MAXB) break;
        for (int i = B + tid; i < NB2; i += 256) hist2[i] = 0;
        hi = B;
        ++round;
        __syncthreads();
    }
}

// Kernel C: per-batch top-100 of 8000: register-cached input, wave-shuffle
// suffix scan, histogram select, rank-sort.
__global__ __launch_bounds__(256) void merge_topk(
    const float* __restrict__ wss, const float4* __restrict__ wsb,
    float* __restrict__ out)
{
    __shared__ int hist[NBIN];
    __shared__ int suf[257];
    __shared__ int wtot[4];
    __shared__ unsigned long long keys[SORT_CAP];
    __shared__ unsigned long long skeys[SORT_CAP];
    __shared__ int sh_B, sh_M;

    int tid = threadIdx.x, b = blockIdx.x;
    int lane = tid & 63, wv = tid >> 6;
    for (int i = tid; i < NBIN / 4; i += 256) ((int4*)hist)[i] = make_int4(0, 0, 0, 0);
    if (tid == 0) sh_M = 0;
    skeys[tid] = 0ULL;
    __syncthreads();

    const float4* w4 = (const float4*)(wss + b * TOT);
    float4 rr[MREG];
#pragma unroll
    for (int k = 0; k < MREG; ++k) {
        int q = tid + k * 256;
        rr[k] = (q < TOTQ) ? w4[q] : make_float4(0, 0, 0, 0);
    }
#pragma unroll
    for (int k = 0; k < MREG; ++k) {
        float4 v = rr[k];
        if (v.x > 0.0f) atomicAdd(&hist[score_bin(v.x)], 1);
        if (v.y > 0.0f) atomicAdd(&hist[score_bin(v.y)], 1);
        if (v.z > 0.0f) atomicAdd(&hist[score_bin(v.z)], 1);
        if (v.w > 0.0f) atomicAdd(&hist[score_bin(v.w)], 1);
    }
    __syncthreads();

    int ps = 0;
#pragma unroll
    for (int u = 0; u < 16; ++u) ps += hist[tid * 16 + u];
    int p = ps;
#pragma unroll
    for (int off = 1; off < 64; off <<= 1) {
        int v = __shfl_down(p, off);
        if (lane + off < 64) p += v;
    }
    if (lane == 0) wtot[wv] = p;
    __syncthreads();
    int add = 0;
    for (int w2 = wv + 1; w2 < 4; ++w2) add += wtot[w2];
    suf[tid] = p + add;
    if (tid == 0) suf[256] = 0;
    __syncthreads();

    int total = suf[0];
    int target = total < MAXB ? total : MAXB;

    if (total > 0) {
        if (suf[tid] >= target && suf[tid + 1] < target) sh_B = tid;
    }
    __syncthreads();
    if (total > 0 && tid == 0) {
        int g = sh_B;
        int running = suf[g + 1];
        int B = g * 16;
        for (int u = 15; u >= 0; --u) {
            running += hist[g * 16 + u];
            if (running >= target) { B = g * 16 + u; break; }
        }
        sh_B = B;
    }
    __syncthreads();
    if (total > 0) {
        int B = sh_B;
#pragma unroll
        for (int k = 0; k < MREG; ++k) {
            int q = tid + k * 256;
            if (q < TOTQ) {
                float4 v = rr[k];
                int ib = q * 4;
                float sv[4] = {v.x, v.y, v.z, v.w};
#pragma unroll
                for (int e = 0; e < 4; ++e) {
                    float s = sv[e];
                    if (s > 0.0f && score_bin(s) >= B) {
                        int pos = atomicAdd(&sh_M, 1);
                        if (pos < SORT_CAP)
                            keys[pos] = ((unsigned long long)__float_as_uint(s) << 32) |
                                        (unsigned)(TOT - 1 - (ib + e));
                    }
                }
            }
        }
    }
    __syncthreads();
    int M = sh_M; if (M > SORT_CAP) M = SORT_CAP;

    unsigned long long mykey = (tid < M) ? keys[tid] : 0ULL;
    int rank = 0;
    for (int j = 0; j < M; ++j) rank += (keys[j] > mykey) ? 1 : 0;
    if (tid < M) skeys[rank] = mykey;
    __syncthreads();

    bool valid = false;
    if (tid < MAXB) {
        unsigned long long g = skeys[tid];
        valid = (g != 0ULL);
        float s = valid ? __uint_as_float((unsigned)(g >> 32)) : 0.0f;
        int f = TOT - 1 - (int)(g & 0xffffffffu);
        float4 bx = make_float4(0, 0, 0, 0);
        float cls = 0.0f;
        if (valid) { bx = wsb[b * TOT + f]; cls = (float)(f / MAXB); }
        ((float4*)out)[b * MAXB + tid] = bx;                          // sel_b
        out[Bn * MAXB * 4 + b * MAXB + tid] = s;                      // sel_s
        out[Bn * MAXB * 5 + b * MAXB + tid] = cls;                    // sel_c
    }
    int nv = __syncthreads_count(valid);
    if (tid == 0) out[Bn * MAXB * 6 + b] = (float)nv;                 // num_valid
}

extern "C" void kernel_launch(void* const* d_in, const int* in_sizes, int n_in,
                              void* d_out, int out_size, void* d_ws, size_t ws_size,
                              hipStream_t stream) {
    const float* boxes = (const float*)d_in[0];
    const float* conf  = (const float*)d_in[1];
    const float* cp    = (const float*)d_in[2];
    float* out = (float*)d_out;

    // workspace (no pre-zeroing: pcnt fully rewritten each run):
    // [0, 327680)            pcnt[B][Cn][CH] packed counts
    // [327680, +10485760)    glist[B][Cn][CH][PCAP] u64 slots
    // offWss                 wss[640*100] f32
    // offWsb                 wsb[640*100] float4
    char* ws = (char*)d_ws;
    int* pcnt = (int*)(ws + 0);
    unsigned long long* glist = (unsigned long long*)(ws + 327680);
    size_t offWss = 327680 + (size_t)Bn * Cn * CH * PCAP * 8;   // 10,813,440
    float* wss = (float*)(ws + offWss);
    size_t offWsb = offWss + (size_t)640 * MAXB * 4;            // 11,069,440
    float4* wsb = (float4*)(ws + offWsb);

    collect<<<Bn * CH, 256, 0, stream>>>(conf, cp, pcnt, glist);
    nms_class<<<Bn * Cn, 256, 0, stream>>>(boxes, conf, cp, pcnt, glist, wss, wsb);
    merge_topk<<<Bn, 256, 0, stream>>>(wss, wsb, out);
}

// Round 10
// 50.653 us; speedup vs baseline: 3.2749x; 1.2974x over previous
//
#include <hip/hip_runtime.h>

#define Bn 8
#define Nn 10647
#define Cn 80
#define MAXB 100
#define SCORE_TH 0.3f
#define BGUESS 0.82f      // cache admission threshold (mean ~184/class, sigma ~13.5)
#define IOU_THR 0.5f
#define NBIN 4096         // merge_topk histogram
#define NB2 1024          // slow-path histogram
#define SORT_CAP 256      // fast-path max candidates AND slow-path chunk
#define TARGET 160
#define CH 128            // chunks per batch in collect
#define PCAP 16           // slots per (chunk,class)
#define TOT (Cn * MAXB)   // 8000
#define TOTQ (TOT / 4)    // 2000
#define MREG 8

__device__ __forceinline__ int score_bin(float s) {
    int v = (int)(__float_as_uint(s) >> 12) - 0x3E999 + 1;
    v = v < 1 ? 1 : v;
    return v > NBIN - 1 ? NBIN - 1 : v;
}
__device__ __forceinline__ int score_bin2(float s) {
    int v = (int)(__float_as_uint(s) >> 14) - 0xFA66 + 1;
    v = v < 1 ? 1 : v;
    return v > NB2 - 1 ? NB2 - 1 : v;
}

// Division-free IoU decision: inter/(aS+aC-inter+1e-9) > 0.5  (symmetric)
__device__ __forceinline__ bool iou_gt(const float4 s, const float4 c) {
    float x1 = fmaxf(s.x, c.x), y1 = fmaxf(s.y, c.y);
    float x2 = fminf(s.z, c.z), y2 = fminf(s.w, c.w);
    float inter = fmaxf(x2 - x1, 0.0f) * fmaxf(y2 - y1, 0.0f);
    float aS = (s.z - s.x) * (s.w - s.y);
    float aC = (c.z - c.x) * (c.w - c.y);
    return inter > IOU_THR * (aS + aC - inter + 1e-9f);
}

// Kernel A: one coalesced pass over cp; no global atomics; [b][c][ch] layout.
__global__ __launch_bounds__(256) void collect(
    const float* __restrict__ conf, const float* __restrict__ cp,
    int* __restrict__ pcnt, unsigned long long* __restrict__ glist)
{
    __shared__ float lconf[88];
    __shared__ int cnt3[Cn];
    __shared__ int cnt9[Cn];
    int tid = threadIdx.x;
    int b = blockIdx.x / CH;
    int ch = blockIdx.x % CH;

    for (int i = tid; i < Cn; i += 256) { cnt3[i] = 0; cnt9[i] = 0; }

    const int totq = Nn * 20;
    const int per = (totq + CH - 1) / CH;           // 1664
    int q0 = ch * per;
    int q1 = q0 + per; if (q1 > totq) q1 = totq;
    int n0 = q0 / 20;
    int nspan = (q1 - 1) / 20 - n0 + 1;             // <= 85

    const float* confB = conf + b * Nn;
    for (int i = tid; i < nspan; i += 256) lconf[i] = confB[n0 + i];
    __syncthreads();

    const float4* cp4 = (const float4*)(cp + (size_t)b * Nn * Cn);

    for (int q = q0 + tid; q < q1; q += 256) {
        float4 v = cp4[q];
        int n = q / 20;
        int c0 = (q % 20) * 4;
        float cf = lconf[n - n0];
        float sv[4] = {v.x, v.y, v.z, v.w};
#pragma unroll
        for (int e = 0; e < 4; ++e) {
            float s = cf * sv[e];
            if (s > SCORE_TH) {
                atomicAdd(&cnt3[c0 + e], 1);
                if (s > BGUESS) {
                    int pos = atomicAdd(&cnt9[c0 + e], 1);   // LDS only
                    if (pos < PCAP)
                        glist[((size_t)(b * Cn + c0 + e) * CH + ch) * PCAP + pos] =
                            ((unsigned long long)__float_as_uint(s) << 32) |
                            (unsigned)(Nn - 1 - n);
                }
            }
        }
    }
    __syncthreads();
    for (int c = tid; c < Cn; c += 256)
        pcnt[(size_t)(b * Cn + c) * CH + ch] = (cnt3[c] & 0xFFFF) | (cnt9[c] << 16);
}

// Kernel B (512 threads): compact -> parity-split rank -> parity-split sorted
// triangle recording <=3 conflict predecessors -> PARALLEL greedy resolution
// -> prefix-scan output. Hard cases -> serial-walk fallback; cache
// insufficiency -> exact slow-path full redo (never in practice).
__global__ __launch_bounds__(512) void nms_class(
    const float* __restrict__ boxes, const float* __restrict__ conf,
    const float* __restrict__ cp,
    const int* __restrict__ pcnt, const unsigned long long* __restrict__ glist,
    float* __restrict__ wss, float4* __restrict__ wsb)
{
    __shared__ unsigned long long keys[SORT_CAP];   // compact keys
    __shared__ float ssc[SORT_CAP];                 // sorted scores
    __shared__ float4 sbx[SORT_CAP];                // sorted boxes
    __shared__ float4 bxu[SORT_CAP];                // slow-path compact boxes
    __shared__ unsigned short cj[SORT_CAP][3];      // conflict predecessor idx
    __shared__ int ncA[SORT_CAP];                   // conflict counts
    __shared__ unsigned char selv[SORT_CAP], resv[SORT_CAP], confl[SORT_CAP];
    __shared__ int rpart[SORT_CAP];
    __shared__ int chc[CH], chOff[CH], pscan[CH];
    __shared__ int hist2[NB2];
    __shared__ int suf[257];
    __shared__ int wtot[4];
    __shared__ int sh_tot, sh_ovf, sh_hard, sh_B, sh_M, sh_nsel;

    int tid = threadIdx.x;
    int lane = tid & 63, wv = tid >> 6;
    int bc = blockIdx.x;
    int b = bc / Cn, c = bc % Cn;

    if (tid == 0) { sh_tot = 0; sh_ovf = 0; sh_hard = 0; sh_nsel = 0; }
    for (int i = tid; i < SORT_CAP; i += 512) ncA[i] = 0;
    __syncthreads();

    // counts + shuffle scan (threads 0..127 = waves 0-1)
    if (tid < CH) {
        int p = pcnt[(size_t)(b * Cn + c) * CH + tid];
        int c9 = p >> 16;
        if (c9 > PCAP) { atomicOr(&sh_ovf, 1); c9 = PCAP; }
        chc[tid] = c9;
        atomicAdd(&sh_tot, p & 0xFFFF);
        int incl = c9;
#pragma unroll
        for (int off = 1; off < 64; off <<= 1) {
            int o = __shfl_up(incl, off);
            if (lane >= off) incl += o;
        }
        pscan[tid] = incl;
    }
    float* ws_s = wss + bc * MAXB;
    float4* ws_b = wsb + bc * MAXB;
    for (int i = tid; i < MAXB; i += 512) ws_s[i] = 0.0f;
    __syncthreads();
    if (tid < CH) {
        int base = (tid >= 64) ? pscan[63] : 0;
        chOff[tid] = base + pscan[tid] - chc[tid];
    }
    __syncthreads();

    int cnt = pscan[63] + pscan[127];
    int tot = sh_tot;
    bool fast = (!sh_ovf) && (cnt <= SORT_CAP);
    int M = fast ? cnt : 0;

    if (fast) {
        const unsigned long long* slotC = glist + (size_t)(b * Cn + c) * CH * PCAP;
        for (int i = tid; i < CH * PCAP; i += 512) {     // 4 coalesced iters
            int ch = i >> 4, j = i & (PCAP - 1);
            if (j < chc[ch]) keys[chOff[ch] + j] = slotC[i];
        }
    }
    __syncthreads();

    const float4* boxesB = (const float4*)boxes + (size_t)b * Nn;
    int cand = tid & 255, half = tid >> 8;
    bool act = (cand < M);

    // Phase A: parity-split rank (uniform-j broadcasts, branchless)
    unsigned long long k0 = 0;
    float4 b0 = make_float4(0, 0, 0, 0);
    if (act) k0 = keys[cand];
    if (act && half == 0) b0 = boxesB[Nn - 1 - (int)(k0 & 0xffffffffu)];
    int r0 = 0;
    if (act) {
#pragma unroll 4
        for (int j = half; j < M; j += 2) r0 += (keys[j] > k0) ? 1 : 0;
    }
    if (act && half == 1) rpart[cand] = r0;
    __syncthreads();
    if (act && half == 0) {
        int rank = r0 + rpart[cand];
        ssc[rank] = __uint_as_float((unsigned)(k0 >> 32));
        sbx[rank] = b0;
    }
    __syncthreads();

    // Phase B: parity-split sorted triangle, record <=3 predecessors
    if (act) {
        float4 tb = sbx[cand];
#pragma unroll 2
        for (int j = half; j < cand; j += 2) {
            float4 bj = sbx[j];                    // broadcast (uniform j)
            if (iou_gt(bj, tb)) {                  // rare
                int s = atomicAdd(&ncA[cand], 1);
                if (s < 3) cj[cand][s] = (unsigned short)j;
            }
        }
    }
    __syncthreads();
    if (tid < SORT_CAP && tid < M && ncA[tid] > 3) atomicOr(&sh_hard, 1);
    __syncthreads();

    if (!sh_hard) {
        // Phase C: parallel greedy resolution (rounds = dependency depth ~2-3)
        bool mysel = false, myres = false;
        if (tid < SORT_CAP) {
            myres = (tid < M) ? (ncA[tid] == 0) : true;
            mysel = (tid < M) && myres;
            selv[tid] = mysel ? 1 : 0;
            resv[tid] = myres ? 1 : 0;
        }
        __syncthreads();
        while (true) {
            bool upd = false, upd_sel = false;
            if (tid < SORT_CAP && tid < M && !myres) {
                int nc = ncA[tid];
                bool allr = true, anysel = false;
                for (int k = 0; k < nc; ++k) {
                    int j = cj[tid][k];
                    allr = allr && (resv[j] != 0);
                    anysel = anysel || (selv[j] != 0);
                }
                if (allr) { upd = true; upd_sel = !anysel; }
            }
            __syncthreads();                       // snapshot stable
            if (upd) {
                myres = true; mysel = upd_sel;
                selv[tid] = mysel ? 1 : 0; resv[tid] = 1;
            }
            int unres = __syncthreads_count((tid < SORT_CAP && tid < M && !myres) ? 1 : 0);
            if (unres == 0) break;
        }
        // prefix scan over sel in sorted order -> output positions
        int v = (tid < SORT_CAP && mysel) ? 1 : 0;
        int incl = v;
        if (tid < SORT_CAP) {
#pragma unroll
            for (int off = 1; off < 64; off <<= 1) {
                int o = __shfl_up(incl, off);
                if (lane >= off) incl += o;
            }
            if (lane == 63) wtot[wv] = incl;
        }
        __syncthreads();
        if (tid < SORT_CAP) {
            int base = 0;
            for (int w = 0; w < wv; ++w) base += wtot[w];
            int pos = base + incl - v;             // exclusive prefix
            if (v && pos < MAXB) { ws_s[pos] = ssc[tid]; ws_b[pos] = sbx[tid]; }
            if (tid == 0) sh_nsel = wtot[0] + wtot[1] + wtot[2] + wtot[3];
        }
        __syncthreads();
    } else {
        // hard fallback: exact serial walk (rare)
        if (tid < SORT_CAP) confl[tid] = (tid < M && ncA[tid] > 0) ? 1 : 0;
        __syncthreads();
        if (tid < 64) {
            float4 sA = make_float4(0, 0, 0, 0), sB = make_float4(0, 0, 0, 0);
            int nsel = 0;
            for (int w0 = 0; w0 < M && nsel < MAXB; w0 += 64) {
                int wlim = M - w0; if (wlim > 64) wlim = 64;
                bool cfl = (tid < wlim) ? (confl[w0 + tid] != 0) : false;
                unsigned long long cmask = __ballot(cfl);
                int pos = 0;
                while (pos < wlim && nsel < MAXB) {
                    if (!((cmask >> pos) & 1ULL)) {
                        unsigned long long rest = cmask >> pos;
                        int run = rest ? (__ffsll(rest) - 1) : (wlim - pos);
                        if (run > wlim - pos) run = wlim - pos;
                        int avail = MAXB - nsel; if (run > avail) run = avail;
                        int d = (tid - (nsel & 63)) & 63;
                        if (d < run) {
                            int s = nsel + d;
                            int ci = w0 + pos + d;
                            float4 bx = sbx[ci];
                            if (s < 64) sA = bx; else sB = bx;
                            ws_s[s] = ssc[ci]; ws_b[s] = bx;
                        }
                        nsel += run; pos += run;
                    } else {
                        int ci = w0 + pos;
                        float4 bx = sbx[ci];
                        bool sup = (tid < nsel) && iou_gt(sA, bx);
                        if (tid + 64 < nsel) sup = sup || iou_gt(sB, bx);
                        if (__ballot(sup) == 0ULL) {
                            if (tid == (nsel & 63)) { if (nsel < 64) sA = bx; else sB = bx; }
                            if (tid == 0) { ws_s[nsel] = ssc[ci]; ws_b[nsel] = bx; }
                            ++nsel;
                        }
                        ++pos;
                    }
                }
            }
            if (tid == 0) sh_nsel = nsel;
        }
        __syncthreads();
    }

    bool needSlow = (!fast) || !((sh_nsel >= MAXB) || (cnt == tot));
    if (!needSlow) return;

    // ---------- slow path: exact full redo (never taken in practice) ----------
    for (int i = tid; i < MAXB; i += 512) ws_s[i] = 0.0f;
    for (int i = tid; i < NB2; i += 512) hist2[i] = 0;
    if (tid == 0) sh_nsel = 0;
    __syncthreads();

    const float* confB = conf + b * Nn;
    const float* cpB = cp + (size_t)b * Nn * Cn + c;
    for (int n = tid; n < Nn; n += 512) {
        float s = confB[n] * cpB[(size_t)n * Cn];
        if (s > SCORE_TH) atomicAdd(&hist2[score_bin2(s)], 1);
    }
    __syncthreads();

    float4 sA = make_float4(0, 0, 0, 0), sB = make_float4(0, 0, 0, 0);
    int hi = NB2;
    int round = 0;

    while (true) {
        if (tid < 256) {
            int ps = 0;
#pragma unroll
            for (int u = 0; u < 4; ++u) ps += hist2[tid * 4 + u];
            int p = ps;
#pragma unroll
            for (int off = 1; off < 64; off <<= 1) {
                int v = __shfl_down(p, off);
                if (lane + off < 64) p += v;
            }
            if (lane == 0) wtot[wv] = p;
        }
        __syncthreads();
        if (tid < 256) {
            int add = 0;
            for (int w2 = wv + 1; w2 < 4; ++w2) add += wtot[w2];
            suf[tid] = ((tid < 256) ? 0 : 0) + add + ((lane < 64) ? 0 : 0);
            // recompute p-part: store via second pass below
        }
        __syncthreads();
        // (rebuild suf properly: suf[t] = inclusive suffix over 4-bin groups)
        if (tid < 256) {
            int ps = 0;
#pragma unroll
            for (int u = 0; u < 4; ++u) ps += hist2[tid * 4 + u];
            int p = ps;
#pragma unroll
            for (int off = 1; off < 64; off <<= 1) {
                int v = __shfl_down(p, off);
                if (lane + off < 64) p += v;
            }
            int add = 0;
            for (int w2 = wv + 1; w2 < 4; ++w2) add += wtot[w2];
            suf[tid] = p + add;
            if (tid == 0) suf[256] = 0;
        }
        __syncthreads();

        int total = suf[0];
        if (total == 0) break;

        int target = total < TARGET ? total : TARGET;
        if (tid < 256 && suf[tid] >= target && suf[tid + 1] < target) sh_B = tid;
        if (tid == 0) sh_M = 0;
        __syncthreads();
        if (tid == 0) {
            int g = sh_B;
            int running = suf[g + 1];
            int B = g * 4;
            for (int u = 3; u >= 0; --u) {
                running += hist2[g * 4 + u];
                if (running >= target) { B = g * 4 + u; break; }
            }
            sh_B = B;
        }
        __syncthreads();
        int B = sh_B;

        for (int n = tid; n < Nn; n += 512) {
            float s = confB[n] * cpB[(size_t)n * Cn];
            if (s > SCORE_TH) {
                int bin = score_bin2(s);
                if (bin >= B && bin < hi) {
                    int pos2 = atomicAdd(&sh_M, 1);
                    if (pos2 < SORT_CAP)
                        keys[pos2] = ((unsigned long long)__float_as_uint(s) << 32) |
                                     (unsigned)(Nn - 1 - n);
                }
            }
        }
        __syncthreads();
        int M2 = sh_M; if (M2 > SORT_CAP) M2 = SORT_CAP;

        unsigned long long mk = 0;
        float4 mb = make_float4(0, 0, 0, 0);
        if (tid < 256) {
            if (tid < M2) { mk = keys[tid]; mb = boxesB[Nn - 1 - (int)(mk & 0xffffffffu)]; }
            bxu[tid] = mb;
        }
        __syncthreads();

        if (tid < 256) {
            int rank = 0;
            bool cfl = (round > 0);
            for (int j = 0; j < M2; ++j) {
                unsigned long long kk = keys[j];
                float4 bj = bxu[j];
                bool gt = kk > mk;
                rank += gt ? 1 : 0;
                if (round == 0) cfl = cfl || (gt && iou_gt(bj, mb));
            }
            if (tid < M2) {
                ssc[rank] = __uint_as_float((unsigned)(mk >> 32));
                sbx[rank] = mb; confl[rank] = cfl ? 1 : 0;
            }
        }
        __syncthreads();

        if (tid < 64) {
            int nsel = sh_nsel;
            for (int w0 = 0; w0 < M2 && nsel < MAXB; w0 += 64) {
                int wlim = M2 - w0; if (wlim > 64) wlim = 64;
                bool cfl2 = (tid < wlim) ? (confl[w0 + tid] != 0) : false;
                unsigned long long cmask = __ballot(cfl2);
                int pos = 0;
                while (pos < wlim && nsel < MAXB) {
                    if (!((cmask >> pos) & 1ULL)) {
                        unsigned long long rest = cmask >> pos;
                        int run = rest ? (__ffsll(rest) - 1) : (wlim - pos);
                        if (run > wlim - pos) run = wlim - pos;
                        int avail = MAXB - nsel; if (run > avail) run = avail;
                        int d = (tid - (nsel & 63)) & 63;
                        if (d < run) {
                            int s = nsel + d;
                            int ci = w0 + pos + d;
                            float4 bx = sbx[ci];
                            if (s < 64) sA = bx; else sB = bx;
                            ws_s[s] = ssc[ci]; ws_b[s] = bx;
                        }
                        nsel += run; pos += run;
                    } else {
                        int ci = w0 + pos;
                        float4 bx = sbx[ci];
                        bool sup = (tid < nsel) && iou_gt(sA, bx);
                        if (tid + 64 < nsel) sup = sup || iou_gt(sB, bx);
                        if (__ballot(sup) == 0ULL) {
                            if (tid == (nsel & 63)) { if (nsel < 64) sA = bx; else sB = bx; }
                            if (tid == 0) { ws_s[nsel] = ssc[ci]; ws_b[nsel] = bx; }
                            ++nsel;
                        }
                        ++pos;
                    }
                }
            }
            if (tid == 0) sh_nsel = nsel;
        }
        __syncthreads();
        if (sh_nsel >= MAXB) break;
        for (int i = B + tid; i < NB2; i += 512) hist2[i] = 0;
        hi = B;
        ++round;
        __syncthreads();
    }
}

// Kernel C: per-batch top-100 of 8000 (unchanged).
__global__ __launch_bounds__(256) void merge_topk(
    const float* __restrict__ wss, const float4* __restrict__ wsb,
    float* __restrict__ out)
{
    __shared__ int hist[NBIN];
    __shared__ int suf[257];
    __shared__ int wtot[4];
    __shared__ unsigned long long keys[SORT_CAP];
    __shared__ unsigned long long skeys[SORT_CAP];
    __shared__ int sh_B, sh_M;

    int tid = threadIdx.x, b = blockIdx.x;
    int lane = tid & 63, wv = tid >> 6;
    for (int i = tid; i < NBIN / 4; i += 256) ((int4*)hist)[i] = make_int4(0, 0, 0, 0);
    if (tid == 0) sh_M = 0;
    skeys[tid] = 0ULL;
    __syncthreads();

    const float4* w4 = (const float4*)(wss + b * TOT);
    float4 rr[MREG];
#pragma unroll
    for (int k = 0; k < MREG; ++k) {
        int q = tid + k * 256;
        rr[k] = (q < TOTQ) ? w4[q] : make_float4(0, 0, 0, 0);
    }
#pragma unroll
    for (int k = 0; k < MREG; ++k) {
        float4 v = rr[k];
        if (v.x > 0.0f) atomicAdd(&hist[score_bin(v.x)], 1);
        if (v.y > 0.0f) atomicAdd(&hist[score_bin(v.y)], 1);
        if (v.z > 0.0f) atomicAdd(&hist[score_bin(v.z)], 1);
        if (v.w > 0.0f) atomicAdd(&hist[score_bin(v.w)], 1);
    }
    __syncthreads();

    int ps = 0;
#pragma unroll
    for (int u = 0; u < 16; ++u) ps += hist[tid * 16 + u];
    int p = ps;
#pragma unroll
    for (int off = 1; off < 64; off <<= 1) {
        int v = __shfl_down(p, off);
        if (lane + off < 64) p += v;
    }
    if (lane == 0) wtot[wv] = p;
    __syncthreads();
    int add = 0;
    for (int w2 = wv + 1; w2 < 4; ++w2) add += wtot[w2];
    suf[tid] = p + add;
    if (tid == 0) suf[256] = 0;
    __syncthreads();

    int total = suf[0];
    int target = total < MAXB ? total : MAXB;

    if (total > 0) {
        if (suf[tid] >= target && suf[tid + 1] < target) sh_B = tid;
    }
    __syncthreads();
    if (total > 0 && tid == 0) {
        int g = sh_B;
        int running = suf[g + 1];
        int B = g * 16;
        for (int u = 15; u >= 0; --u) {
            running += hist[g * 16 + u];
            if (running >= target) { B = g * 16 + u; break; }
        }
        sh_B = B;
    }
    __syncthreads();
    if (total > 0) {
        int B = sh_B;
#pragma unroll
        for (int k = 0; k < MREG; ++k) {
            int q = tid + k * 256;
            if (q < TOTQ) {
                float4 v = rr[k];
                int ib = q * 4;
                float sv[4] = {v.x, v.y, v.z, v.w};
#pragma unroll
                for (int e = 0; e < 4; ++e) {
                    float s = sv[e];
                    if (s > 0.0f && score_bin(s) >= B) {
                        int pos = atomicAdd(&sh_M, 1);
                        if (pos < SORT_CAP)
                            keys[pos] = ((unsigned long long)__float_as_uint(s) << 32) |
                                        (unsigned)(TOT - 1 - (ib + e));
                    }
                }
            }
        }
    }
    __syncthreads();
    int M = sh_M; if (M > SORT_CAP) M = SORT_CAP;

    unsigned long long mykey = (tid < M) ? keys[tid] : 0ULL;
    int rank = 0;
    for (int j = 0; j < M; ++j) rank += (keys[j] > mykey) ? 1 : 0;
    if (tid < M) skeys[rank] = mykey;
    __syncthreads();

    bool valid = false;
    if (tid < MAXB) {
        unsigned long long g = skeys[tid];
        valid = (g != 0ULL);
        float s = valid ? __uint_as_float((unsigned)(g >> 32)) : 0.0f;
        int f = TOT - 1 - (int)(g & 0xffffffffu);
        float4 bx = make_float4(0, 0, 0, 0);
        float cls = 0.0f;
        if (valid) { bx = wsb[b * TOT + f]; cls = (float)(f / MAXB); }
        ((float4*)out)[b * MAXB + tid] = bx;                          // sel_b
        out[Bn * MAXB * 4 + b * MAXB + tid] = s;                      // sel_s
        out[Bn * MAXB * 5 + b * MAXB + tid] = cls;                    // sel_c
    }
    int nv = __syncthreads_count(valid);
    if (tid == 0) out[Bn * MAXB * 6 + b] = (float)nv;                 // num_valid
}

extern "C" void kernel_launch(void* const* d_in, const int* in_sizes, int n_in,
                              void* d_out, int out_size, void* d_ws, size_t ws_size,
                              hipStream_t stream) {
    const float* boxes = (const float*)d_in[0];
    const float* conf  = (const float*)d_in[1];
    const float* cp    = (const float*)d_in[2];
    float* out = (float*)d_out;

    char* ws = (char*)d_ws;
    int* pcnt = (int*)(ws + 0);
    unsigned long long* glist = (unsigned long long*)(ws + 327680);
    size_t offWss = 327680 + (size_t)Bn * Cn * CH * PCAP * 8;   // 10,813,440
    float* wss = (float*)(ws + offWss);
    size_t offWsb = offWss + (size_t)640 * MAXB * 4;            // 11,069,440
    float4* wsb = (float4*)(ws + offWsb);

    collect<<<Bn * CH, 256, 0, stream>>>(conf, cp, pcnt, glist);
    nms_class<<<Bn * Cn, 512, 0, stream>>>(boxes, conf, cp, pcnt, glist, wss, wsb);
    merge_topk<<<Bn, 256, 0, stream>>>(wss, wsb, out);
}